// Round 3
// baseline (687.352 us; speedup 1.0000x reference)
//
#include <hip/hip_runtime.h>
#include <cstdint>

typedef unsigned short u16;
typedef __attribute__((ext_vector_type(8))) short bf16x8;
typedef __attribute__((ext_vector_type(4))) float f32x4;

#define DEV static __device__ __forceinline__

static constexpr int Bb = 4, Tt = 512, Nn = 1024, Dd = 1024, Hh = 16;
static constexpr float NEGV = -10000.0f;

DEV u16 f2bf(float f) {
  unsigned int u = __builtin_bit_cast(unsigned int, f);
  u += 0x7fffu + ((u >> 16) & 1u);
  return (u16)(u >> 16);
}
DEV float bf2f(u16 s) {
  unsigned int u = ((unsigned int)s) << 16;
  return __builtin_bit_cast(float, u);
}
DEV f32x4 mfma16(bf16x8 a, bf16x8 b, f32x4 c) {
  return __builtin_amdgcn_mfma_f32_16x16x32_bf16(a, b, c, 0, 0, 0);
}

// ---------------- transpose + cast: src[R][C] f32 -> dst[C][R] bf16 -------------
__global__ __launch_bounds__(256) void transpose_cast(const float* __restrict__ src,
                                                      u16* __restrict__ dst, int R, int C) {
  __shared__ float tile[32][33];
  const int c0 = blockIdx.x * 32, r0 = blockIdx.y * 32;
  const int tx = threadIdx.x, ty = threadIdx.y;
#pragma unroll
  for (int j = 0; j < 4; ++j)
    tile[ty + 8 * j][tx] = src[(size_t)(r0 + ty + 8 * j) * C + c0 + tx];
  __syncthreads();
#pragma unroll
  for (int j = 0; j < 4; ++j)
    dst[(size_t)(c0 + ty + 8 * j) * R + r0 + tx] = f2bf(tile[tx][ty + 8 * j]);
}

// ---------------- silu(c) -> bf16 -------------
__global__ __launch_bounds__(256) void silu_k(const float* __restrict__ c, u16* __restrict__ o, int n) {
  int i = blockIdx.x * 256 + threadIdx.x;
  if (i < n) { float x = c[i]; o[i] = f2bf(x / (1.0f + __expf(-x))); }
}

// ---------------- build concat [q2 | q] bf16 -------------
__global__ __launch_bounds__(256) void cat_k(const float* __restrict__ q2, const float* __restrict__ qr,
                                             u16* __restrict__ cat) {
  int i = blockIdx.x * 256 + threadIdx.x;  // over 4096*1024
  int r = i >> 10, c = i & 1023;
  cat[(size_t)r * 2048 + c] = f2bf(q2[i]);
  cat[(size_t)r * 2048 + 1024 + c] = f2bf(qr[i]);
}

// ---------------- adaLN-modulated layernorm: out = bf16(ln(x)*(1+scale)+shift) -------------
__global__ __launch_bounds__(256) void ln_mod_k(const float* __restrict__ X, const u16* __restrict__ MOD,
                                                u16* __restrict__ OUT, int chunk) {
  const int row = blockIdx.x;             // 0..4095
  const int b = row >> 10, i = row & 1023, t = i >> 1;
  const int tid = threadIdx.x;
  const float4 xv = *(const float4*)&X[(size_t)row * 1024 + tid * 4];
  float s = xv.x + xv.y + xv.z + xv.w;
  float q = xv.x * xv.x + xv.y * xv.y + xv.z * xv.z + xv.w * xv.w;
#pragma unroll
  for (int off = 32; off > 0; off >>= 1) { s += __shfl_down(s, off); q += __shfl_down(q, off); }
  __shared__ float rs[4], rq[4];
  if ((tid & 63) == 0) { rs[tid >> 6] = s; rq[tid >> 6] = q; }
  __syncthreads();
  float S = rs[0] + rs[1] + rs[2] + rs[3];
  float Q = rq[0] + rq[1] + rq[2] + rq[3];
  const float mu = S * (1.0f / 1024.0f);
  const float var = Q * (1.0f / 1024.0f) - mu * mu;
  const float rstd = rsqrtf(var + 1e-6f);
  const u16* mrow = MOD + (size_t)(b * Tt + t) * 6144 + chunk * 1024 + tid * 4;
  u16* out = OUT + (size_t)row * 1024 + tid * 4;
  const float xx[4] = {xv.x, xv.y, xv.z, xv.w};
#pragma unroll
  for (int j = 0; j < 4; ++j) {
    float sc = bf2f(mrow[j]);
    float sh = bf2f(mrow[1024 + j]);
    out[j] = f2bf((xx[j] - mu) * rstd * (1.0f + sc) + sh);
  }
}

// ---------------- kin = ln(c+pe)*gk+bk ; vin = ln(c)*gv+bv -------------
__global__ __launch_bounds__(256) void ln_kv_k(const float* __restrict__ C_, const float* __restrict__ PE,
                                               const float* __restrict__ gk, const float* __restrict__ bk,
                                               const float* __restrict__ gv, const float* __restrict__ bv,
                                               u16* __restrict__ KIN, u16* __restrict__ VIN) {
  const int row = blockIdx.x, tid = threadIdx.x;  // rows 0..2047
  const size_t base = (size_t)row * 1024 + tid * 4;
  const float4 cv = *(const float4*)&C_[base];
  const float4 pv = *(const float4*)&PE[base];
  const float a[4] = {cv.x + pv.x, cv.y + pv.y, cv.z + pv.z, cv.w + pv.w};
  const float bb[4] = {cv.x, cv.y, cv.z, cv.w};
  float sa = a[0] + a[1] + a[2] + a[3];
  float qa = a[0] * a[0] + a[1] * a[1] + a[2] * a[2] + a[3] * a[3];
  float sb = bb[0] + bb[1] + bb[2] + bb[3];
  float qb = bb[0] * bb[0] + bb[1] * bb[1] + bb[2] * bb[2] + bb[3] * bb[3];
#pragma unroll
  for (int off = 32; off > 0; off >>= 1) {
    sa += __shfl_down(sa, off); qa += __shfl_down(qa, off);
    sb += __shfl_down(sb, off); qb += __shfl_down(qb, off);
  }
  __shared__ float r4[4][4];
  if ((tid & 63) == 0) {
    int w = tid >> 6;
    r4[0][w] = sa; r4[1][w] = qa; r4[2][w] = sb; r4[3][w] = qb;
  }
  __syncthreads();
  sa = r4[0][0] + r4[0][1] + r4[0][2] + r4[0][3];
  qa = r4[1][0] + r4[1][1] + r4[1][2] + r4[1][3];
  sb = r4[2][0] + r4[2][1] + r4[2][2] + r4[2][3];
  qb = r4[3][0] + r4[3][1] + r4[3][2] + r4[3][3];
  const float mua = sa * (1.0f / 1024.0f);
  const float ra = rsqrtf(qa * (1.0f / 1024.0f) - mua * mua + 1e-5f);
  const float mub = sb * (1.0f / 1024.0f);
  const float rb = rsqrtf(qb * (1.0f / 1024.0f) - mub * mub + 1e-5f);
#pragma unroll
  for (int j = 0; j < 4; ++j) {
    int d = tid * 4 + j;
    KIN[(size_t)row * 1024 + d] = f2bf((a[j] - mua) * ra * gk[d] + bk[d]);
    VIN[(size_t)row * 1024 + d] = f2bf((bb[j] - mub) * rb * gv[d] + bv[d]);
  }
}

// ---------------- GEMM: C[M,N] = A[M,K](bf16) @ Bt[N,K](bf16)^T, epilogues -------------
// EPI 0: bf16 out            1: bf16 + bias          2: bf16 + bias + exact-gelu
// EPI 3: f32 + bias + res    4: f32 + bias           5: f32 = (1+acc+bias)*q2 + res
template <int EPI>
__global__ __launch_bounds__(256) void gemm_k(const u16* __restrict__ A, const u16* __restrict__ Bt,
                                              int M, int N, int K,
                                              const float* __restrict__ bias,
                                              const float* res, const float* q2,
                                              float* outf, u16* outb) {
  __shared__ u16 As[128][72];
  __shared__ u16 Bs[128][72];
  const int tid = threadIdx.x;
  const int l = tid & 63, wid = tid >> 6;
  const int wr = wid >> 1, wc = wid & 1;
  const int fr = l & 15, fg = l >> 4;
  const int brow = blockIdx.y * 128, bcol = blockIdx.x * 128;

  f32x4 acc[4][4];
#pragma unroll
  for (int m = 0; m < 4; ++m)
#pragma unroll
    for (int n = 0; n < 4; ++n) acc[m][n] = (f32x4){0.f, 0.f, 0.f, 0.f};

  const int nk = K >> 6;
  for (int kt = 0; kt < nk; ++kt) {
    const int kbase = kt << 6;
#pragma unroll
    for (int p = 0; p < 4; ++p) {
      int cid = tid + (p << 8);
      int row = cid >> 3, kof = (cid & 7) << 3;
      *(uint4*)&As[row][kof] = *(const uint4*)&A[(size_t)(brow + row) * K + kbase + kof];
      *(uint4*)&Bs[row][kof] = *(const uint4*)&Bt[(size_t)(bcol + row) * K + kbase + kof];
    }
    __syncthreads();
#pragma unroll
    for (int kk = 0; kk < 64; kk += 32) {
      bf16x8 af[4], bfr[4];
#pragma unroll
      for (int m = 0; m < 4; ++m) af[m] = *(const bf16x8*)&As[wr * 64 + m * 16 + fr][kk + fg * 8];
#pragma unroll
      for (int n = 0; n < 4; ++n) bfr[n] = *(const bf16x8*)&Bs[wc * 64 + n * 16 + fr][kk + fg * 8];
#pragma unroll
      for (int m = 0; m < 4; ++m)
#pragma unroll
        for (int n = 0; n < 4; ++n) acc[m][n] = mfma16(af[m], bfr[n], acc[m][n]);
    }
    __syncthreads();
  }

#pragma unroll
  for (int m = 0; m < 4; ++m)
#pragma unroll
    for (int n = 0; n < 4; ++n)
#pragma unroll
      for (int r = 0; r < 4; ++r) {
        const int row = brow + wr * 64 + m * 16 + fg * 4 + r;
        const int col = bcol + wc * 64 + n * 16 + fr;
        const size_t o = (size_t)row * N + col;
        float v = acc[m][n][r];
        if (EPI != 0) v += bias[col];
        if (EPI == 2) v = 0.5f * v * (1.0f + erff(v * 0.70710678118f));
        if (EPI <= 2) outb[o] = f2bf(v);
        else if (EPI == 3) outf[o] = v + res[o];
        else if (EPI == 4) outf[o] = v;
        else outf[o] = (1.0f + v) * q2[o] + res[o];
      }
}

// ---------------- flash attention over head slices of [B*Nq, 1024] buffers -------------
// qdiv: 1 (SA causal j<=i) or 2 (CA: j<=i/2); pdiv: pad index = key/pdiv into pmask[B][T]
// NOTE: iterates ALL Nk tiles — the reference's mask is finite (-1e4), so masked keys
// still carry softmax weight when a row's whole visible window is padded. No early exit.
__global__ __launch_bounds__(256) void attn_k(const u16* __restrict__ QH, const u16* __restrict__ KH,
                                              const u16* __restrict__ VH, u16* __restrict__ AO,
                                              const int* __restrict__ pmask,
                                              int Nq, int Nk, int qdiv, int pdiv) {
  __shared__ u16 Ks[32][72];   // 32 keys x 64 d (+8 pad)
  __shared__ u16 Vt[64][40];   // 64 d x 32 keys (+8 pad)
  __shared__ u16 Pl[4][16][40];
  const int tid = threadIdx.x;
  const int l = tid & 63, wid = tid >> 6;
  const int fr = l & 15, fg = l >> 4;
  const int nqb = Nq >> 6;
  const int qb = blockIdx.x % nqb;
  const int bh = blockIdx.x / nqb;
  const int h = bh & 15, b = bh >> 4;
  const int q0 = qb * 64 + wid * 16;

  const size_t qrow = (size_t)(b * Nq + q0 + fr) * Dd + h * 64;
  const bf16x8 aq0 = *(const bf16x8*)&QH[qrow + fg * 8];
  const bf16x8 aq1 = *(const bf16x8*)&QH[qrow + 32 + fg * 8];

  f32x4 o[4];
#pragma unroll
  for (int c = 0; c < 4; ++c) o[c] = (f32x4){0.f, 0.f, 0.f, 0.f};
  float mrun[4] = {-3e38f, -3e38f, -3e38f, -3e38f};
  float lrun[4] = {0.f, 0.f, 0.f, 0.f};

  const int nkt = Nk >> 5;   // ALL tiles (reference semantics; no causal early-exit)

  const int srow = tid >> 3, skof = (tid & 7) << 3;
  for (int kt = 0; kt < nkt; ++kt) {
    const int kb = kt << 5;
    {
      const size_t g = (size_t)(b * Nk + kb + srow) * Dd + h * 64 + skof;
      *(uint4*)&Ks[srow][skof] = *(const uint4*)&KH[g];
      union { uint4 u; u16 s[8]; } uv;
      uv.u = *(const uint4*)&VH[g];
#pragma unroll
      for (int j = 0; j < 8; ++j) Vt[skof + j][srow] = uv.s[j];
    }
    __syncthreads();

    f32x4 s0 = (f32x4){0.f, 0.f, 0.f, 0.f}, s1 = (f32x4){0.f, 0.f, 0.f, 0.f};
    {
      bf16x8 kf;
      kf = *(const bf16x8*)&Ks[fr][fg * 8];        s0 = mfma16(aq0, kf, s0);
      kf = *(const bf16x8*)&Ks[fr][32 + fg * 8];   s0 = mfma16(aq1, kf, s0);
      kf = *(const bf16x8*)&Ks[16 + fr][fg * 8];       s1 = mfma16(aq0, kf, s1);
      kf = *(const bf16x8*)&Ks[16 + fr][32 + fg * 8];  s1 = mfma16(aq1, kf, s1);
    }
    const int c0 = kb + fr, c1 = kb + 16 + fr;
    const float pad0 = pmask[b * Tt + c0 / pdiv] ? NEGV : 0.0f;
    const float pad1 = pmask[b * Tt + c1 / pdiv] ? NEGV : 0.0f;

#pragma unroll
    for (int r = 0; r < 4; ++r) {
      const int rq = (q0 + fg * 4 + r) / qdiv;
      float v0 = s0[r] * 0.125f; v0 = (c0 <= rq) ? v0 : NEGV; v0 += pad0;
      float v1 = s1[r] * 0.125f; v1 = (c1 <= rq) ? v1 : NEGV; v1 += pad1;
      float tm = fmaxf(v0, v1);
      tm = fmaxf(tm, __shfl_xor(tm, 1));
      tm = fmaxf(tm, __shfl_xor(tm, 2));
      tm = fmaxf(tm, __shfl_xor(tm, 4));
      tm = fmaxf(tm, __shfl_xor(tm, 8));
      const float mn = fmaxf(mrun[r], tm);
      const float fsc = __expf(mrun[r] - mn);
      const float p0 = __expf(v0 - mn), p1 = __expf(v1 - mn);
      float rsum = p0 + p1;
      rsum += __shfl_xor(rsum, 1);
      rsum += __shfl_xor(rsum, 2);
      rsum += __shfl_xor(rsum, 4);
      rsum += __shfl_xor(rsum, 8);
      lrun[r] = lrun[r] * fsc + rsum;
      mrun[r] = mn;
#pragma unroll
      for (int c = 0; c < 4; ++c) o[c][r] *= fsc;
      Pl[wid][fg * 4 + r][fr] = f2bf(p0);
      Pl[wid][fg * 4 + r][16 + fr] = f2bf(p1);
    }

    const bf16x8 pa = *(const bf16x8*)&Pl[wid][fr][fg * 8];
#pragma unroll
    for (int c = 0; c < 4; ++c) {
      const bf16x8 vb = *(const bf16x8*)&Vt[c * 16 + fr][fg * 8];
      o[c] = mfma16(pa, vb, o[c]);
    }
    __syncthreads();
  }

#pragma unroll
  for (int c = 0; c < 4; ++c)
#pragma unroll
    for (int r = 0; r < 4; ++r) {
      const int row = q0 + fg * 4 + r;
      AO[(size_t)(b * Nq + row) * Dd + h * 64 + c * 16 + fr] = f2bf(o[c][r] / lrun[r]);
    }
}

// =======================================================================================
extern "C" void kernel_launch(void* const* d_in, const int* in_sizes, int n_in,
                              void* d_out, int out_size, void* d_ws, size_t ws_size,
                              hipStream_t stream) {
  (void)in_sizes; (void)n_in; (void)out_size; (void)ws_size;
  const float* q_in   = (const float*)d_in[0];
  const float* c_in   = (const float*)d_in[1];
  const float* pe     = (const float*)d_in[2];
  const int*   pmask  = (const int*)d_in[3];
  const float* w_mod  = (const float*)d_in[4];
  const float* b_mod  = (const float*)d_in[5];
  const float* sa_wq  = (const float*)d_in[6];
  const float* sa_wk  = (const float*)d_in[7];
  const float* sa_wv  = (const float*)d_in[8];
  const float* sa_wo  = (const float*)d_in[9];
  const float* sa_bo  = (const float*)d_in[10];
  const float* ca_wq  = (const float*)d_in[11];
  const float* ca_wk  = (const float*)d_in[12];
  const float* ca_wv  = (const float*)d_in[13];
  const float* ca_wo  = (const float*)d_in[14];
  const float* ca_bo  = (const float*)d_in[15];
  const float* gk     = (const float*)d_in[16];
  const float* bk     = (const float*)d_in[17];
  const float* gv     = (const float*)d_in[18];
  const float* bv     = (const float*)d_in[19];
  const float* w_alpha= (const float*)d_in[20];
  const float* b_alpha= (const float*)d_in[21];
  const float* w1     = (const float*)d_in[22];
  const float* b1     = (const float*)d_in[23];
  const float* w2     = (const float*)d_in[24];
  const float* b2     = (const float*)d_in[25];

  // ---- workspace layout (u16 element offsets); total ~155 MB ----
  u16* ws = (u16*)d_ws;
  u16* WMODt  = ws + 0;                     // [6144][1024]
  u16* SAWQt  = ws + 6291456;               // [1024][1024] each
  u16* SAWKt  = ws + 7340032;
  u16* SAWVt  = ws + 8388608;
  u16* SAWOt  = ws + 9437184;
  u16* CAWQt  = ws + 10485760;
  u16* CAWKt  = ws + 11534336;
  u16* CAWVt  = ws + 12582912;
  u16* CAWOt  = ws + 13631488;
  u16* WALPHt = ws + 14680064;              // [1024][2048]
  u16* W1t    = ws + 16777216;              // [4096][1024]
  u16* W2t    = ws + 20971520;              // [1024][4096]
  u16* Xs     = ws + 25165824;              // [2048][1024] silu(c)
  u16* MODbf  = ws + 27262976;              // [2048][6144]
  u16* LNO    = ws + 39845888;              // [4096][1024]
  u16* BIG    = ws + 44040192;              // 16M elems, multi-use
  u16* QHp = BIG, *KHp = BIG + 4194304, *VHp = BIG + 8388608, *AOp = BIG + 12582912;
  u16* KINp = AOp, *VINp = AOp + 2097152;   // CA K/V inputs (overlay AO)
  u16* CATp = BIG;                          // [4096][2048] (overlay, post-CA)
  u16* HBp  = BIG;                          // [4096][4096] MLP hidden (overlay)
  float* Qres = (float*)(ws + 60817408);    // [4096][1024] f32
  float* Q2f  = Qres + 4194304;             // [4096][1024] f32
  float* outp = (float*)d_out;

  const dim3 blk(256);
  auto TR = [&](const float* s, u16* d, int R, int C) {
    transpose_cast<<<dim3(C / 32, R / 32), dim3(32, 8), 0, stream>>>(s, d, R, C);
  };

  // weights -> bf16 transposed
  TR(w_mod, WMODt, 1024, 6144);
  TR(sa_wq, SAWQt, 1024, 1024); TR(sa_wk, SAWKt, 1024, 1024);
  TR(sa_wv, SAWVt, 1024, 1024); TR(sa_wo, SAWOt, 1024, 1024);
  TR(ca_wq, CAWQt, 1024, 1024); TR(ca_wk, CAWKt, 1024, 1024);
  TR(ca_wv, CAWVt, 1024, 1024); TR(ca_wo, CAWOt, 1024, 1024);
  TR(w_alpha, WALPHt, 2048, 1024);
  TR(w1, W1t, 1024, 4096);
  TR(w2, W2t, 4096, 1024);

  // modulation
  silu_k<<<8192, blk, 0, stream>>>(c_in, Xs, 2048 * 1024);
  gemm_k<1><<<dim3(48, 16), blk, 0, stream>>>(Xs, WMODt, 2048, 6144, 1024, b_mod, nullptr, nullptr, nullptr, MODbf);

  // ---- self-attention ----
  ln_mod_k<<<4096, blk, 0, stream>>>(q_in, MODbf, LNO, 0);
  gemm_k<0><<<dim3(8, 32), blk, 0, stream>>>(LNO, SAWQt, 4096, 1024, 1024, nullptr, nullptr, nullptr, nullptr, QHp);
  gemm_k<0><<<dim3(8, 32), blk, 0, stream>>>(LNO, SAWKt, 4096, 1024, 1024, nullptr, nullptr, nullptr, nullptr, KHp);
  gemm_k<0><<<dim3(8, 32), blk, 0, stream>>>(LNO, SAWVt, 4096, 1024, 1024, nullptr, nullptr, nullptr, nullptr, VHp);
  attn_k<<<1024, blk, 0, stream>>>(QHp, KHp, VHp, AOp, pmask, 1024, 1024, 1, 2);
  gemm_k<3><<<dim3(8, 32), blk, 0, stream>>>(AOp, SAWOt, 4096, 1024, 1024, sa_bo, q_in, nullptr, Qres, nullptr);

  // ---- cross-attention ----
  ln_mod_k<<<4096, blk, 0, stream>>>(Qres, MODbf, LNO, 2);
  ln_kv_k<<<2048, blk, 0, stream>>>(c_in, pe, gk, bk, gv, bv, KINp, VINp);
  gemm_k<0><<<dim3(8, 32), blk, 0, stream>>>(LNO, CAWQt, 4096, 1024, 1024, nullptr, nullptr, nullptr, nullptr, QHp);
  gemm_k<0><<<dim3(8, 16), blk, 0, stream>>>(KINp, CAWKt, 2048, 1024, 1024, nullptr, nullptr, nullptr, nullptr, KHp);
  gemm_k<0><<<dim3(8, 16), blk, 0, stream>>>(VINp, CAWVt, 2048, 1024, 1024, nullptr, nullptr, nullptr, nullptr, VHp);
  attn_k<<<1024, blk, 0, stream>>>(QHp, KHp, VHp, AOp, pmask, 1024, 512, 2, 1);
  gemm_k<4><<<dim3(8, 32), blk, 0, stream>>>(AOp, CAWOt, 4096, 1024, 1024, ca_bo, nullptr, nullptr, Q2f, nullptr);
  cat_k<<<16384, blk, 0, stream>>>(Q2f, Qres, CATp);
  gemm_k<5><<<dim3(8, 32), blk, 0, stream>>>(CATp, WALPHt, 4096, 1024, 2048, b_alpha, Qres, Q2f, Qres, nullptr);

  // ---- MLP ----
  ln_mod_k<<<4096, blk, 0, stream>>>(Qres, MODbf, LNO, 4);
  gemm_k<2><<<dim3(32, 32), blk, 0, stream>>>(LNO, W1t, 4096, 4096, 1024, b1, nullptr, nullptr, nullptr, HBp);
  gemm_k<3><<<dim3(8, 32), blk, 0, stream>>>(HBp, W2t, 4096, 1024, 4096, b2, Qres, nullptr, outp, nullptr);
}

// Round 4
// 674.430 us; speedup vs baseline: 1.0192x; 1.0192x over previous
//
#include <hip/hip_runtime.h>
#include <cstdint>

typedef unsigned short u16;
typedef __attribute__((ext_vector_type(8))) short bf16x8;
typedef __attribute__((ext_vector_type(4))) float f32x4;

#define DEV static __device__ __forceinline__
#define AS1 __attribute__((address_space(1)))
#define AS3 __attribute__((address_space(3)))

static constexpr int Bb = 4, Tt = 512, Nn = 1024, Dd = 1024, Hh = 16;
static constexpr float NEGV = -10000.0f;

DEV u16 f2bf(float f) {
  unsigned int u = __builtin_bit_cast(unsigned int, f);
  u += 0x7fffu + ((u >> 16) & 1u);
  return (u16)(u >> 16);
}
DEV float bf2f(u16 s) {
  unsigned int u = ((unsigned int)s) << 16;
  return __builtin_bit_cast(float, u);
}
DEV f32x4 mfma16(bf16x8 a, bf16x8 b, f32x4 c) {
  return __builtin_amdgcn_mfma_f32_16x16x32_bf16(a, b, c, 0, 0, 0);
}
// async global->LDS, 16B per lane; LDS dest must be wave-uniform base (+lane*16 implied)
DEV void gload16(const u16* g, u16* lds) {
  __builtin_amdgcn_global_load_lds((AS1 const unsigned int*)g, (AS3 unsigned int*)lds, 16, 0, 0);
}

// ---------------- transpose + cast: src[R][C] f32 -> dst[C][R] bf16 -------------
__global__ __launch_bounds__(256) void transpose_cast(const float* __restrict__ src,
                                                      u16* __restrict__ dst, int R, int C) {
  __shared__ float tile[32][33];
  const int c0 = blockIdx.x * 32, r0 = blockIdx.y * 32;
  const int tx = threadIdx.x, ty = threadIdx.y;
#pragma unroll
  for (int j = 0; j < 4; ++j)
    tile[ty + 8 * j][tx] = src[(size_t)(r0 + ty + 8 * j) * C + c0 + tx];
  __syncthreads();
#pragma unroll
  for (int j = 0; j < 4; ++j)
    dst[(size_t)(c0 + ty + 8 * j) * R + r0 + tx] = f2bf(tile[tx][ty + 8 * j]);
}

// ---------------- silu(c) -> bf16 -------------
__global__ __launch_bounds__(256) void silu_k(const float* __restrict__ c, u16* __restrict__ o, int n) {
  int i = blockIdx.x * 256 + threadIdx.x;
  if (i < n) { float x = c[i]; o[i] = f2bf(x / (1.0f + __expf(-x))); }
}

// ---------------- build concat [q2 | q] bf16 -------------
__global__ __launch_bounds__(256) void cat_k(const float* __restrict__ q2, const float* __restrict__ qr,
                                             u16* __restrict__ cat) {
  int i = blockIdx.x * 256 + threadIdx.x;  // over 4096*1024
  int r = i >> 10, c = i & 1023;
  cat[(size_t)r * 2048 + c] = f2bf(q2[i]);
  cat[(size_t)r * 2048 + 1024 + c] = f2bf(qr[i]);
}

// ---------------- per-(b,t) softmax scale M: 0 if any unpadded token in prefix, else -1e4 ----
__global__ __launch_bounds__(64) void mrow_k(const int* __restrict__ pm, float* __restrict__ M) {
  const int tid = threadIdx.x;            // 64 threads: 4 batches x 16 segments of 32
  const int b = tid >> 4, seg = tid & 15;
  int pre[32];
  int a = 1;
#pragma unroll
  for (int j = 0; j < 32; ++j) { a &= pm[b * 512 + seg * 32 + j]; pre[j] = a; }
  const int total = a;
  int excl = 1;
  for (int s = 0; s < 16; ++s) {
    int o = __shfl(total, (b << 4) + s, 64);
    if (s < seg) excl &= o;
  }
#pragma unroll
  for (int j = 0; j < 32; ++j)
    M[b * 512 + seg * 32 + j] = (excl & pre[j]) ? NEGV : 0.0f;
}

// ---------------- adaLN-modulated layernorm: out = bf16(ln(x)*(1+scale)+shift) -------------
__global__ __launch_bounds__(256) void ln_mod_k(const float* __restrict__ X, const u16* __restrict__ MOD,
                                                u16* __restrict__ OUT, int chunk) {
  const int row = blockIdx.x;             // 0..4095
  const int b = row >> 10, i = row & 1023, t = i >> 1;
  const int tid = threadIdx.x;
  const float4 xv = *(const float4*)&X[(size_t)row * 1024 + tid * 4];
  float s = xv.x + xv.y + xv.z + xv.w;
  float q = xv.x * xv.x + xv.y * xv.y + xv.z * xv.z + xv.w * xv.w;
#pragma unroll
  for (int off = 32; off > 0; off >>= 1) { s += __shfl_down(s, off); q += __shfl_down(q, off); }
  __shared__ float rs[4], rq[4];
  if ((tid & 63) == 0) { rs[tid >> 6] = s; rq[tid >> 6] = q; }
  __syncthreads();
  float S = rs[0] + rs[1] + rs[2] + rs[3];
  float Q = rq[0] + rq[1] + rq[2] + rq[3];
  const float mu = S * (1.0f / 1024.0f);
  const float var = Q * (1.0f / 1024.0f) - mu * mu;
  const float rstd = rsqrtf(var + 1e-6f);
  const u16* mrow = MOD + (size_t)(b * Tt + t) * 6144 + chunk * 1024 + tid * 4;
  u16* out = OUT + (size_t)row * 1024 + tid * 4;
  const float xx[4] = {xv.x, xv.y, xv.z, xv.w};
#pragma unroll
  for (int j = 0; j < 4; ++j) {
    float sc = bf2f(mrow[j]);
    float sh = bf2f(mrow[1024 + j]);
    out[j] = f2bf((xx[j] - mu) * rstd * (1.0f + sc) + sh);
  }
}

// ---------------- kin = ln(c+pe)*gk+bk ; vin = ln(c)*gv+bv -------------
__global__ __launch_bounds__(256) void ln_kv_k(const float* __restrict__ C_, const float* __restrict__ PE,
                                               const float* __restrict__ gk, const float* __restrict__ bk,
                                               const float* __restrict__ gv, const float* __restrict__ bv,
                                               u16* __restrict__ KIN, u16* __restrict__ VIN) {
  const int row = blockIdx.x, tid = threadIdx.x;  // rows 0..2047
  const size_t base = (size_t)row * 1024 + tid * 4;
  const float4 cv = *(const float4*)&C_[base];
  const float4 pv = *(const float4*)&PE[base];
  const float a[4] = {cv.x + pv.x, cv.y + pv.y, cv.z + pv.z, cv.w + pv.w};
  const float bb[4] = {cv.x, cv.y, cv.z, cv.w};
  float sa = a[0] + a[1] + a[2] + a[3];
  float qa = a[0] * a[0] + a[1] * a[1] + a[2] * a[2] + a[3] * a[3];
  float sb = bb[0] + bb[1] + bb[2] + bb[3];
  float qb = bb[0] * bb[0] + bb[1] * bb[1] + bb[2] * bb[2] + bb[3] * bb[3];
#pragma unroll
  for (int off = 32; off > 0; off >>= 1) {
    sa += __shfl_down(sa, off); qa += __shfl_down(qa, off);
    sb += __shfl_down(sb, off); qb += __shfl_down(qb, off);
  }
  __shared__ float r4[4][4];
  if ((tid & 63) == 0) {
    int w = tid >> 6;
    r4[0][w] = sa; r4[1][w] = qa; r4[2][w] = sb; r4[3][w] = qb;
  }
  __syncthreads();
  sa = r4[0][0] + r4[0][1] + r4[0][2] + r4[0][3];
  qa = r4[1][0] + r4[1][1] + r4[1][2] + r4[1][3];
  sb = r4[2][0] + r4[2][1] + r4[2][2] + r4[2][3];
  qb = r4[3][0] + r4[3][1] + r4[3][2] + r4[3][3];
  const float mua = sa * (1.0f / 1024.0f);
  const float ra = rsqrtf(qa * (1.0f / 1024.0f) - mua * mua + 1e-5f);
  const float mub = sb * (1.0f / 1024.0f);
  const float rb = rsqrtf(qb * (1.0f / 1024.0f) - mub * mub + 1e-5f);
#pragma unroll
  for (int j = 0; j < 4; ++j) {
    int d = tid * 4 + j;
    KIN[(size_t)row * 1024 + d] = f2bf((a[j] - mua) * ra * gk[d] + bk[d]);
    VIN[(size_t)row * 1024 + d] = f2bf((bb[j] - mub) * rb * gv[d] + bv[d]);
  }
}

// ---------------- GEMM: C[M,N] = A[M,K](bf16) @ Bt[N,K](bf16)^T, epilogues -------------
// global_load_lds (width 16) staging into linear [128][64] LDS tiles (m97 pattern).
// EPI 0: bf16 out            1: bf16 + bias          2: bf16 + bias + exact-gelu
// EPI 3: f32 + bias + res    4: f32 + bias           5: f32 = (1+acc+bias)*q2 + res
template <int EPI>
__global__ __launch_bounds__(256) void gemm_k(const u16* __restrict__ A, const u16* __restrict__ Bt,
                                              int M, int N, int K,
                                              const float* __restrict__ bias,
                                              const float* res, const float* q2,
                                              float* outf, u16* outb) {
  __shared__ u16 As[128][64];
  __shared__ u16 Bs[128][64];
  const int tid = threadIdx.x;
  const int l = tid & 63, wid = tid >> 6;
  const int wr = wid >> 1, wc = wid & 1;
  const int fr = l & 15, fg = l >> 4;
  const int brow = blockIdx.y * 128, bcol = blockIdx.x * 128;
  const int lrow = l >> 3, lkof = (l & 7) << 3;   // lane's row-in-chunk / k-offset

  f32x4 acc[4][4];
#pragma unroll
  for (int m = 0; m < 4; ++m)
#pragma unroll
    for (int n = 0; n < 4; ++n) acc[m][n] = (f32x4){0.f, 0.f, 0.f, 0.f};

  const int nk = K >> 6;
  for (int kt = 0; kt < nk; ++kt) {
    const int kbase = kt << 6;
#pragma unroll
    for (int p = 0; p < 4; ++p) {
      const int c = (wid << 2) + p;       // chunk 0..15 = rows 8c..8c+7
      const int row = (c << 3) + lrow;
      gload16(&A[(size_t)(brow + row) * K + kbase + lkof], &As[c << 3][0]);
      gload16(&Bt[(size_t)(bcol + row) * K + kbase + lkof], &Bs[c << 3][0]);
    }
    __syncthreads();
#pragma unroll
    for (int kk = 0; kk < 64; kk += 32) {
      bf16x8 af[4], bfr[4];
#pragma unroll
      for (int m = 0; m < 4; ++m) af[m] = *(const bf16x8*)&As[wr * 64 + m * 16 + fr][kk + fg * 8];
#pragma unroll
      for (int n = 0; n < 4; ++n) bfr[n] = *(const bf16x8*)&Bs[wc * 64 + n * 16 + fr][kk + fg * 8];
#pragma unroll
      for (int m = 0; m < 4; ++m)
#pragma unroll
        for (int n = 0; n < 4; ++n) acc[m][n] = mfma16(af[m], bfr[n], acc[m][n]);
    }
    __syncthreads();
  }

#pragma unroll
  for (int m = 0; m < 4; ++m)
#pragma unroll
    for (int n = 0; n < 4; ++n)
#pragma unroll
      for (int r = 0; r < 4; ++r) {
        const int row = brow + wr * 64 + m * 16 + fg * 4 + r;
        const int col = bcol + wc * 64 + n * 16 + fr;
        const size_t o = (size_t)row * N + col;
        float v = acc[m][n][r];
        if (EPI != 0) v += bias[col];
        if (EPI == 2) v = 0.5f * v * (1.0f + erff(v * 0.70710678118f));
        if (EPI <= 2) outb[o] = f2bf(v);
        else if (EPI == 3) outf[o] = v + res[o];
        else if (EPI == 4) outf[o] = v;
        else outf[o] = (1.0f + v) * q2[o] + res[o];
      }
}

// ---------------- flash attention over head slices of [B*Nq, 1024] buffers -------------
// Softmax uses precomputed per-row scale M (0 or -1e4): p = exp(v - M). Exactly matches
// the reference's finite-mask softmax in both regimes (masked keys underflow to 0 when
// M=0; all-padded-window rows use M=-1e4). No per-tile max/sum reduction needed.
// Early exit past the causal frontier allowed iff block's first row has M==0 (monotone).
__global__ __launch_bounds__(256) void attn_k(const u16* __restrict__ QH, const u16* __restrict__ KH,
                                              const u16* __restrict__ VH, u16* __restrict__ AO,
                                              const int* __restrict__ pmask, const float* __restrict__ Mrow,
                                              int Nq, int Nk, int qdiv, int pdiv) {
  __shared__ u16 Ks[32][72];   // 32 keys x 64 d (+8 pad)
  __shared__ u16 Vt[64][40];   // 64 d x 32 keys (+8 pad)
  __shared__ u16 Pl[4][16][40];
  const int tid = threadIdx.x;
  const int l = tid & 63, wid = tid >> 6;
  const int fr = l & 15, fg = l >> 4;
  const int nqb = Nq >> 6;
  const int qb = blockIdx.x % nqb;
  const int bh = blockIdx.x / nqb;
  const int h = bh & 15, b = bh >> 4;
  const int q0 = qb * 64 + wid * 16;

  const size_t qrow = (size_t)(b * Nq + q0 + fr) * Dd + h * 64;
  const bf16x8 aq0 = *(const bf16x8*)&QH[qrow + fg * 8];
  const bf16x8 aq1 = *(const bf16x8*)&QH[qrow + 32 + fg * 8];

  float Mr[4];
#pragma unroll
  for (int r = 0; r < 4; ++r) Mr[r] = Mrow[b * Tt + ((q0 + fg * 4 + r) >> 1)];

  f32x4 o[4];
#pragma unroll
  for (int c = 0; c < 4; ++c) o[c] = (f32x4){0.f, 0.f, 0.f, 0.f};
  float lsum[4] = {0.f, 0.f, 0.f, 0.f};

  int nkt = Nk >> 5;
  if (Mrow[b * Tt + ((qb * 64) >> 1)] == 0.0f) {   // whole block in regime M=0 -> causal exit ok
    const int kallow = (qb * 64 + 63) / qdiv + 1;
    const int t = (kallow + 31) >> 5;
    if (t < nkt) nkt = t;
  }

  const int srow = tid >> 3, skof = (tid & 7) << 3;
  for (int kt = 0; kt < nkt; ++kt) {
    const int kb = kt << 5;
    {
      const size_t g = (size_t)(b * Nk + kb + srow) * Dd + h * 64 + skof;
      *(uint4*)&Ks[srow][skof] = *(const uint4*)&KH[g];
      union { uint4 u; u16 s[8]; } uv;
      uv.u = *(const uint4*)&VH[g];
#pragma unroll
      for (int j = 0; j < 8; ++j) Vt[skof + j][srow] = uv.s[j];
    }
    __syncthreads();

    f32x4 s0 = (f32x4){0.f, 0.f, 0.f, 0.f}, s1 = (f32x4){0.f, 0.f, 0.f, 0.f};
    {
      bf16x8 kf;
      kf = *(const bf16x8*)&Ks[fr][fg * 8];        s0 = mfma16(aq0, kf, s0);
      kf = *(const bf16x8*)&Ks[fr][32 + fg * 8];   s0 = mfma16(aq1, kf, s0);
      kf = *(const bf16x8*)&Ks[16 + fr][fg * 8];       s1 = mfma16(aq0, kf, s1);
      kf = *(const bf16x8*)&Ks[16 + fr][32 + fg * 8];  s1 = mfma16(aq1, kf, s1);
    }
    const int c0 = kb + fr, c1 = kb + 16 + fr;
    const float pad0 = pmask[b * Tt + c0 / pdiv] ? NEGV : 0.0f;
    const float pad1 = pmask[b * Tt + c1 / pdiv] ? NEGV : 0.0f;

#pragma unroll
    for (int r = 0; r < 4; ++r) {
      const int rq = (q0 + fg * 4 + r) / qdiv;
      float v0 = s0[r] * 0.125f; v0 = (c0 <= rq) ? v0 : NEGV; v0 += pad0;
      float v1 = s1[r] * 0.125f; v1 = (c1 <= rq) ? v1 : NEGV; v1 += pad1;
      const float p0 = __expf(v0 - Mr[r]);
      const float p1 = __expf(v1 - Mr[r]);
      lsum[r] += p0 + p1;
      Pl[wid][fg * 4 + r][fr] = f2bf(p0);
      Pl[wid][fg * 4 + r][16 + fr] = f2bf(p1);
    }

    const bf16x8 pa = *(const bf16x8*)&Pl[wid][fr][fg * 8];
#pragma unroll
    for (int c = 0; c < 4; ++c) {
      const bf16x8 vb = *(const bf16x8*)&Vt[c * 16 + fr][fg * 8];
      o[c] = mfma16(pa, vb, o[c]);
    }
    __syncthreads();
  }

#pragma unroll
  for (int r = 0; r < 4; ++r) {
    lsum[r] += __shfl_xor(lsum[r], 1);
    lsum[r] += __shfl_xor(lsum[r], 2);
    lsum[r] += __shfl_xor(lsum[r], 4);
    lsum[r] += __shfl_xor(lsum[r], 8);
  }

#pragma unroll
  for (int c = 0; c < 4; ++c)
#pragma unroll
    for (int r = 0; r < 4; ++r) {
      const int row = q0 + fg * 4 + r;
      AO[(size_t)(b * Nq + row) * Dd + h * 64 + c * 16 + fr] = f2bf(o[c][r] / lsum[r]);
    }
}

// =======================================================================================
extern "C" void kernel_launch(void* const* d_in, const int* in_sizes, int n_in,
                              void* d_out, int out_size, void* d_ws, size_t ws_size,
                              hipStream_t stream) {
  (void)in_sizes; (void)n_in; (void)out_size; (void)ws_size;
  const float* q_in   = (const float*)d_in[0];
  const float* c_in   = (const float*)d_in[1];
  const float* pe     = (const float*)d_in[2];
  const int*   pmask  = (const int*)d_in[3];
  const float* w_mod  = (const float*)d_in[4];
  const float* b_mod  = (const float*)d_in[5];
  const float* sa_wq  = (const float*)d_in[6];
  const float* sa_wk  = (const float*)d_in[7];
  const float* sa_wv  = (const float*)d_in[8];
  const float* sa_wo  = (const float*)d_in[9];
  const float* sa_bo  = (const float*)d_in[10];
  const float* ca_wq  = (const float*)d_in[11];
  const float* ca_wk  = (const float*)d_in[12];
  const float* ca_wv  = (const float*)d_in[13];
  const float* ca_wo  = (const float*)d_in[14];
  const float* ca_bo  = (const float*)d_in[15];
  const float* gk     = (const float*)d_in[16];
  const float* bk     = (const float*)d_in[17];
  const float* gv     = (const float*)d_in[18];
  const float* bv     = (const float*)d_in[19];
  const float* w_alpha= (const float*)d_in[20];
  const float* b_alpha= (const float*)d_in[21];
  const float* w1     = (const float*)d_in[22];
  const float* b1     = (const float*)d_in[23];
  const float* w2     = (const float*)d_in[24];
  const float* b2     = (const float*)d_in[25];

  // ---- workspace layout (u16 element offsets); total ~155 MB ----
  u16* ws = (u16*)d_ws;
  u16* WMODt  = ws + 0;                     // [6144][1024]
  u16* SAWQt  = ws + 6291456;               // [1024][1024] each
  u16* SAWKt  = ws + 7340032;
  u16* SAWVt  = ws + 8388608;
  u16* SAWOt  = ws + 9437184;
  u16* CAWQt  = ws + 10485760;
  u16* CAWKt  = ws + 11534336;
  u16* CAWVt  = ws + 12582912;
  u16* CAWOt  = ws + 13631488;
  u16* WALPHt = ws + 14680064;              // [1024][2048]
  u16* W1t    = ws + 16777216;              // [4096][1024]
  u16* W2t    = ws + 20971520;              // [1024][4096]
  u16* Xs     = ws + 25165824;              // [2048][1024] silu(c); dead after mod GEMM
  float* Mp   = (float*)(ws + 25165824);    // [4][512] overlay on dead Xs (written after mod GEMM)
  u16* MODbf  = ws + 27262976;              // [2048][6144]
  u16* LNO    = ws + 39845888;              // [4096][1024]
  u16* BIG    = ws + 44040192;              // 16M elems, multi-use
  u16* QHp = BIG, *KHp = BIG + 4194304, *VHp = BIG + 8388608, *AOp = BIG + 12582912;
  u16* KINp = AOp, *VINp = AOp + 2097152;   // CA K/V inputs (overlay AO)
  u16* CATp = BIG;                          // [4096][2048] (overlay, post-CA)
  u16* HBp  = BIG;                          // [4096][4096] MLP hidden (overlay)
  float* Qres = (float*)(ws + 60817408);    // [4096][1024] f32
  float* Q2f  = Qres + 4194304;             // [4096][1024] f32
  float* outp = (float*)d_out;

  const dim3 blk(256);
  auto TR = [&](const float* s, u16* d, int R, int C) {
    transpose_cast<<<dim3(C / 32, R / 32), dim3(32, 8), 0, stream>>>(s, d, R, C);
  };

  // weights -> bf16 transposed
  TR(w_mod, WMODt, 1024, 6144);
  TR(sa_wq, SAWQt, 1024, 1024); TR(sa_wk, SAWKt, 1024, 1024);
  TR(sa_wv, SAWVt, 1024, 1024); TR(sa_wo, SAWOt, 1024, 1024);
  TR(ca_wq, CAWQt, 1024, 1024); TR(ca_wk, CAWKt, 1024, 1024);
  TR(ca_wv, CAWVt, 1024, 1024); TR(ca_wo, CAWOt, 1024, 1024);
  TR(w_alpha, WALPHt, 2048, 1024);
  TR(w1, W1t, 1024, 4096);
  TR(w2, W2t, 4096, 1024);

  // modulation
  silu_k<<<8192, blk, 0, stream>>>(c_in, Xs, 2048 * 1024);
  gemm_k<1><<<dim3(48, 16), blk, 0, stream>>>(Xs, WMODt, 2048, 6144, 1024, b_mod, nullptr, nullptr, nullptr, MODbf);
  mrow_k<<<1, 64, 0, stream>>>(pmask, Mp);   // after mod GEMM (Mp overlays Xs)

  // ---- self-attention ----
  ln_mod_k<<<4096, blk, 0, stream>>>(q_in, MODbf, LNO, 0);
  gemm_k<0><<<dim3(8, 32), blk, 0, stream>>>(LNO, SAWQt, 4096, 1024, 1024, nullptr, nullptr, nullptr, nullptr, QHp);
  gemm_k<0><<<dim3(8, 32), blk, 0, stream>>>(LNO, SAWKt, 4096, 1024, 1024, nullptr, nullptr, nullptr, nullptr, KHp);
  gemm_k<0><<<dim3(8, 32), blk, 0, stream>>>(LNO, SAWVt, 4096, 1024, 1024, nullptr, nullptr, nullptr, nullptr, VHp);
  attn_k<<<1024, blk, 0, stream>>>(QHp, KHp, VHp, AOp, pmask, Mp, 1024, 1024, 1, 2);
  gemm_k<3><<<dim3(8, 32), blk, 0, stream>>>(AOp, SAWOt, 4096, 1024, 1024, sa_bo, q_in, nullptr, Qres, nullptr);

  // ---- cross-attention ----
  ln_mod_k<<<4096, blk, 0, stream>>>(Qres, MODbf, LNO, 2);
  ln_kv_k<<<2048, blk, 0, stream>>>(c_in, pe, gk, bk, gv, bv, KINp, VINp);
  gemm_k<0><<<dim3(8, 32), blk, 0, stream>>>(LNO, CAWQt, 4096, 1024, 1024, nullptr, nullptr, nullptr, nullptr, QHp);
  gemm_k<0><<<dim3(8, 16), blk, 0, stream>>>(KINp, CAWKt, 2048, 1024, 1024, nullptr, nullptr, nullptr, nullptr, KHp);
  gemm_k<0><<<dim3(8, 16), blk, 0, stream>>>(VINp, CAWVt, 2048, 1024, 1024, nullptr, nullptr, nullptr, nullptr, VHp);
  attn_k<<<1024, blk, 0, stream>>>(QHp, KHp, VHp, AOp, pmask, Mp, 1024, 512, 2, 1);
  gemm_k<4><<<dim3(8, 32), blk, 0, stream>>>(AOp, CAWOt, 4096, 1024, 1024, ca_bo, nullptr, nullptr, Q2f, nullptr);
  cat_k<<<16384, blk, 0, stream>>>(Q2f, Qres, CATp);
  gemm_k<5><<<dim3(8, 32), blk, 0, stream>>>(CATp, WALPHt, 4096, 1024, 2048, b_alpha, Qres, Q2f, Qres, nullptr);

  // ---- MLP ----
  ln_mod_k<<<4096, blk, 0, stream>>>(Qres, MODbf, LNO, 4);
  gemm_k<2><<<dim3(32, 32), blk, 0, stream>>>(LNO, W1t, 4096, 4096, 1024, b1, nullptr, nullptr, nullptr, HBp);
  gemm_k<3><<<dim3(8, 32), blk, 0, stream>>>(HBp, W2t, 4096, 1024, 4096, b2, Qres, nullptr, outp, nullptr);
}

// Round 5
// 642.711 us; speedup vs baseline: 1.0695x; 1.0494x over previous
//
#include <hip/hip_runtime.h>
#include <cstdint>

typedef unsigned short u16;
typedef __attribute__((ext_vector_type(8))) short bf16x8;
typedef __attribute__((ext_vector_type(4))) float f32x4;

#define DEV static __device__ __forceinline__
#define AS1 __attribute__((address_space(1)))
#define AS3 __attribute__((address_space(3)))

static constexpr int Bb = 4, Tt = 512, Nn = 1024, Dd = 1024, Hh = 16;
static constexpr float NEGV = -10000.0f;

DEV u16 f2bf(float f) {
  unsigned int u = __builtin_bit_cast(unsigned int, f);
  u += 0x7fffu + ((u >> 16) & 1u);
  return (u16)(u >> 16);
}
DEV float bf2f(u16 s) {
  unsigned int u = ((unsigned int)s) << 16;
  return __builtin_bit_cast(float, u);
}
DEV f32x4 mfma16(bf16x8 a, bf16x8 b, f32x4 c) {
  return __builtin_amdgcn_mfma_f32_16x16x32_bf16(a, b, c, 0, 0, 0);
}
DEV void gload16(const u16* g, u16* lds) {
  __builtin_amdgcn_global_load_lds((AS1 const unsigned int*)g, (AS3 unsigned int*)lds, 16, 0, 0);
}
// chunked XCD swizzle; requires nwg % 8 == 0
DEV int swz8(int wg, int nwg) { const int c = nwg >> 3; return (wg & 7) * c + (wg >> 3); }

// ---------------- transpose + cast: src[R][C] f32 -> dst[C][R] bf16 -------------
__global__ __launch_bounds__(256) void transpose_cast(const float* __restrict__ src,
                                                      u16* __restrict__ dst, int R, int C) {
  __shared__ float tile[32][33];
  const int c0 = blockIdx.x * 32, r0 = blockIdx.y * 32;
  const int tx = threadIdx.x, ty = threadIdx.y;
#pragma unroll
  for (int j = 0; j < 4; ++j)
    tile[ty + 8 * j][tx] = src[(size_t)(r0 + ty + 8 * j) * C + c0 + tx];
  __syncthreads();
#pragma unroll
  for (int j = 0; j < 4; ++j)
    dst[(size_t)(c0 + ty + 8 * j) * R + r0 + tx] = f2bf(tile[tx][ty + 8 * j]);
}

// ---------------- silu(c) -> bf16 -------------
__global__ __launch_bounds__(256) void silu_k(const float* __restrict__ c, u16* __restrict__ o, int n) {
  int i = blockIdx.x * 256 + threadIdx.x;
  if (i < n) { float x = c[i]; o[i] = f2bf(x / (1.0f + __expf(-x))); }
}

// ---------------- build concat [q2 | q] bf16 -------------
__global__ __launch_bounds__(256) void cat_k(const float* __restrict__ q2, const float* __restrict__ qr,
                                             u16* __restrict__ cat) {
  int i = blockIdx.x * 256 + threadIdx.x;  // over 4096*1024
  int r = i >> 10, c = i & 1023;
  cat[(size_t)r * 2048 + c] = f2bf(q2[i]);
  cat[(size_t)r * 2048 + 1024 + c] = f2bf(qr[i]);
}

// ---------------- out[row][col] = bias[col] (+ res[row][col]) ; f32, vectorized -------------
__global__ __launch_bounds__(256) void init_k(float* __restrict__ out, const float* __restrict__ bias,
                                              const float* __restrict__ res) {
  const int i = blockIdx.x * 256 + threadIdx.x;          // float4 index over 4096x1024
  const float4 bv = ((const float4*)bias)[i & 255];
  float4 v = bv;
  if (res) {
    const float4 rv = ((const float4*)res)[i];
    v.x += rv.x; v.y += rv.y; v.z += rv.z; v.w += rv.w;
  }
  ((float4*)out)[i] = v;
}

// ---------------- qres = (1+alp)*q2 + qres -------------
__global__ __launch_bounds__(256) void comb_k(const float* __restrict__ alp, const float* __restrict__ q2,
                                              float* __restrict__ qres) {
  const int i = blockIdx.x * 256 + threadIdx.x;          // float4 index
  const float4 a = ((const float4*)alp)[i];
  const float4 b = ((const float4*)q2)[i];
  float4 r = ((float4*)qres)[i];
  r.x += (1.0f + a.x) * b.x; r.y += (1.0f + a.y) * b.y;
  r.z += (1.0f + a.z) * b.z; r.w += (1.0f + a.w) * b.w;
  ((float4*)qres)[i] = r;
}

// ---------------- per-(b,t) softmax scale M: -1e4 if whole prefix padded, else 0 ----
__global__ __launch_bounds__(64) void mrow_k(const int* __restrict__ pm, float* __restrict__ M) {
  const int tid = threadIdx.x;            // 4 batches x 16 segments of 32
  const int b = tid >> 4, seg = tid & 15;
  int pre[32];
  int a = 1;
#pragma unroll
  for (int j = 0; j < 32; ++j) { a &= pm[b * 512 + seg * 32 + j]; pre[j] = a; }
  const int total = a;
  int excl = 1;
  for (int s = 0; s < 16; ++s) {
    int o = __shfl(total, (b << 4) + s, 64);
    if (s < seg) excl &= o;
  }
#pragma unroll
  for (int j = 0; j < 32; ++j)
    M[b * 512 + seg * 32 + j] = (excl & pre[j]) ? NEGV : 0.0f;
}

// ---------------- adaLN-modulated layernorm -------------
__global__ __launch_bounds__(256) void ln_mod_k(const float* __restrict__ X, const u16* __restrict__ MOD,
                                                u16* __restrict__ OUT, int chunk) {
  const int row = blockIdx.x;             // 0..4095
  const int b = row >> 10, i = row & 1023, t = i >> 1;
  const int tid = threadIdx.x;
  const float4 xv = *(const float4*)&X[(size_t)row * 1024 + tid * 4];
  float s = xv.x + xv.y + xv.z + xv.w;
  float q = xv.x * xv.x + xv.y * xv.y + xv.z * xv.z + xv.w * xv.w;
#pragma unroll
  for (int off = 32; off > 0; off >>= 1) { s += __shfl_down(s, off); q += __shfl_down(q, off); }
  __shared__ float rs[4], rq[4];
  if ((tid & 63) == 0) { rs[tid >> 6] = s; rq[tid >> 6] = q; }
  __syncthreads();
  float S = rs[0] + rs[1] + rs[2] + rs[3];
  float Q = rq[0] + rq[1] + rq[2] + rq[3];
  const float mu = S * (1.0f / 1024.0f);
  const float var = Q * (1.0f / 1024.0f) - mu * mu;
  const float rstd = rsqrtf(var + 1e-6f);
  const u16* mrow = MOD + (size_t)(b * Tt + t) * 6144 + chunk * 1024 + tid * 4;
  u16* out = OUT + (size_t)row * 1024 + tid * 4;
  const float xx[4] = {xv.x, xv.y, xv.z, xv.w};
#pragma unroll
  for (int j = 0; j < 4; ++j) {
    float sc = bf2f(mrow[j]);
    float sh = bf2f(mrow[1024 + j]);
    out[j] = f2bf((xx[j] - mu) * rstd * (1.0f + sc) + sh);
  }
}

// ---------------- kin = ln(c+pe)*gk+bk ; vin = ln(c)*gv+bv -------------
__global__ __launch_bounds__(256) void ln_kv_k(const float* __restrict__ C_, const float* __restrict__ PE,
                                               const float* __restrict__ gk, const float* __restrict__ bk,
                                               const float* __restrict__ gv, const float* __restrict__ bv,
                                               u16* __restrict__ KIN, u16* __restrict__ VIN) {
  const int row = blockIdx.x, tid = threadIdx.x;  // rows 0..2047
  const size_t base = (size_t)row * 1024 + tid * 4;
  const float4 cv = *(const float4*)&C_[base];
  const float4 pv = *(const float4*)&PE[base];
  const float a[4] = {cv.x + pv.x, cv.y + pv.y, cv.z + pv.z, cv.w + pv.w};
  const float bb[4] = {cv.x, cv.y, cv.z, cv.w};
  float sa = a[0] + a[1] + a[2] + a[3];
  float qa = a[0] * a[0] + a[1] * a[1] + a[2] * a[2] + a[3] * a[3];
  float sb = bb[0] + bb[1] + bb[2] + bb[3];
  float qb = bb[0] * bb[0] + bb[1] * bb[1] + bb[2] * bb[2] + bb[3] * bb[3];
#pragma unroll
  for (int off = 32; off > 0; off >>= 1) {
    sa += __shfl_down(sa, off); qa += __shfl_down(qa, off);
    sb += __shfl_down(sb, off); qb += __shfl_down(qb, off);
  }
  __shared__ float r4[4][4];
  if ((tid & 63) == 0) {
    int w = tid >> 6;
    r4[0][w] = sa; r4[1][w] = qa; r4[2][w] = sb; r4[3][w] = qb;
  }
  __syncthreads();
  sa = r4[0][0] + r4[0][1] + r4[0][2] + r4[0][3];
  qa = r4[1][0] + r4[1][1] + r4[1][2] + r4[1][3];
  sb = r4[2][0] + r4[2][1] + r4[2][2] + r4[2][3];
  qb = r4[3][0] + r4[3][1] + r4[3][2] + r4[3][3];
  const float mua = sa * (1.0f / 1024.0f);
  const float ra = rsqrtf(qa * (1.0f / 1024.0f) - mua * mua + 1e-5f);
  const float mub = sb * (1.0f / 1024.0f);
  const float rb = rsqrtf(qb * (1.0f / 1024.0f) - mub * mub + 1e-5f);
#pragma unroll
  for (int j = 0; j < 4; ++j) {
    int d = tid * 4 + j;
    KIN[(size_t)row * 1024 + d] = f2bf((a[j] - mua) * ra * gk[d] + bk[d]);
    VIN[(size_t)row * 1024 + d] = f2bf((bb[j] - mub) * rb * gv[d] + bv[d]);
  }
}

// ---------------- shared 128x128 GEMM core: acc += A[brow..][kt0*64..kt1*64) x Bt^T ----
DEV void gcore(const u16* __restrict__ A, const u16* __restrict__ Bt, int K,
               int brow, int bcol, int kt0, int kt1,
               u16 (*As)[64], u16 (*Bs)[64], f32x4 (&acc)[4][4]) {
  const int tid = threadIdx.x;
  const int l = tid & 63, wid = tid >> 6;
  const int wr = wid >> 1, wc = wid & 1;
  const int fr = l & 15, fg = l >> 4;
  const int lrow = l >> 3, lkof = (l & 7) << 3;
  for (int kt = kt0; kt < kt1; ++kt) {
    const int kbase = kt << 6;
#pragma unroll
    for (int p = 0; p < 4; ++p) {
      const int c = (wid << 2) + p;
      const int row = (c << 3) + lrow;
      gload16(&A[(size_t)(brow + row) * K + kbase + lkof], &As[c << 3][0]);
      gload16(&Bt[(size_t)(bcol + row) * K + kbase + lkof], &Bs[c << 3][0]);
    }
    __syncthreads();
#pragma unroll
    for (int kk = 0; kk < 64; kk += 32) {
      bf16x8 af[4], bfr[4];
#pragma unroll
      for (int m = 0; m < 4; ++m) af[m] = *(const bf16x8*)&As[wr * 64 + m * 16 + fr][kk + fg * 8];
#pragma unroll
      for (int n = 0; n < 4; ++n) bfr[n] = *(const bf16x8*)&Bs[wc * 64 + n * 16 + fr][kk + fg * 8];
#pragma unroll
      for (int m = 0; m < 4; ++m)
#pragma unroll
        for (int n = 0; n < 4; ++n) acc[m][n] = mfma16(af[m], bfr[n], acc[m][n]);
    }
    __syncthreads();
  }
}

// ---------------- generic GEMM, 1D swizzled grid -------------
// EPI 0: bf16 out   1: bf16+bias   2: bf16+bias+exact-gelu
template <int EPI>
__global__ __launch_bounds__(256) void gemm_k(const u16* __restrict__ A, const u16* __restrict__ Bt,
                                              int N, int K, const float* __restrict__ bias,
                                              u16* __restrict__ outb, int nbx) {
  __shared__ u16 As[128][64];
  __shared__ u16 Bs[128][64];
  const int wg = swz8(blockIdx.x, gridDim.x);
  const int brow = (wg / nbx) * 128, bcol = (wg % nbx) * 128;
  const int l = threadIdx.x & 63, wid = threadIdx.x >> 6;
  const int wr = wid >> 1, wc = wid & 1, fr = l & 15, fg = l >> 4;
  f32x4 acc[4][4];
#pragma unroll
  for (int m = 0; m < 4; ++m)
#pragma unroll
    for (int n = 0; n < 4; ++n) acc[m][n] = (f32x4){0.f, 0.f, 0.f, 0.f};
  gcore(A, Bt, K, brow, bcol, 0, K >> 6, As, Bs, acc);
#pragma unroll
  for (int m = 0; m < 4; ++m)
#pragma unroll
    for (int n = 0; n < 4; ++n)
#pragma unroll
      for (int r = 0; r < 4; ++r) {
        const int row = brow + wr * 64 + m * 16 + fg * 4 + r;
        const int col = bcol + wc * 64 + n * 16 + fr;
        float v = acc[m][n][r];
        if (EPI != 0) v += bias[col];
        if (EPI == 2) v = 0.5f * v * (1.0f + erff(v * 0.70710678118f));
        outb[(size_t)row * N + col] = f2bf(v);
      }
}

// ---------------- split-K=2 GEMM, f32 atomicAdd epilogue (deterministic: 2 commutative adds) ----
__global__ __launch_bounds__(256) void gemm_sk(const u16* __restrict__ A, const u16* __restrict__ Bt,
                                               int N, int K, float* __restrict__ outf, int nbx) {
  __shared__ u16 As[128][64];
  __shared__ u16 Bs[128][64];
  const int wg = swz8(blockIdx.x, gridDim.x);
  const int brow = (wg / nbx) * 128, bcol = (wg % nbx) * 128;
  const int half = K >> 7;                       // k-tiles per half
  const int kt0 = blockIdx.y * half;
  const int l = threadIdx.x & 63, wid = threadIdx.x >> 6;
  const int wr = wid >> 1, wc = wid & 1, fr = l & 15, fg = l >> 4;
  f32x4 acc[4][4];
#pragma unroll
  for (int m = 0; m < 4; ++m)
#pragma unroll
    for (int n = 0; n < 4; ++n) acc[m][n] = (f32x4){0.f, 0.f, 0.f, 0.f};
  gcore(A, Bt, K, brow, bcol, kt0, kt0 + half, As, Bs, acc);
#pragma unroll
  for (int m = 0; m < 4; ++m)
#pragma unroll
    for (int n = 0; n < 4; ++n)
#pragma unroll
      for (int r = 0; r < 4; ++r) {
        const int row = brow + wr * 64 + m * 16 + fg * 4 + r;
        const int col = bcol + wc * 64 + n * 16 + fr;
        atomicAdd(&outf[(size_t)row * N + col], acc[m][n][r]);
      }
}

// ---------------- CA grouped GEMM: z=0 Q(M=4096), z=1 K(M=2048), z=2 V(M=2048); N=K=1024 ----
__global__ __launch_bounds__(256) void gemm3_k(const u16* A0, const u16* A1, const u16* A2,
                                               const u16* B0, const u16* B1, const u16* B2,
                                               u16* O0, u16* O1, u16* O2) {
  const int z = blockIdx.y;
  const int wg = swz8(blockIdx.x, gridDim.x);
  const int bx = wg & 7, by = wg >> 3;
  if (z > 0 && by >= 16) return;
  const u16* A = z == 0 ? A0 : (z == 1 ? A1 : A2);
  const u16* Bt = z == 0 ? B0 : (z == 1 ? B1 : B2);
  u16* O = z == 0 ? O0 : (z == 1 ? O1 : O2);
  __shared__ u16 As[128][64];
  __shared__ u16 Bs[128][64];
  const int brow = by * 128, bcol = bx * 128;
  const int l = threadIdx.x & 63, wid = threadIdx.x >> 6;
  const int wr = wid >> 1, wc = wid & 1, fr = l & 15, fg = l >> 4;
  f32x4 acc[4][4];
#pragma unroll
  for (int m = 0; m < 4; ++m)
#pragma unroll
    for (int n = 0; n < 4; ++n) acc[m][n] = (f32x4){0.f, 0.f, 0.f, 0.f};
  gcore(A, Bt, 1024, brow, bcol, 0, 16, As, Bs, acc);
#pragma unroll
  for (int m = 0; m < 4; ++m)
#pragma unroll
    for (int n = 0; n < 4; ++n)
#pragma unroll
      for (int r = 0; r < 4; ++r) {
        const int row = brow + wr * 64 + m * 16 + fg * 4 + r;
        const int col = bcol + wc * 64 + n * 16 + fr;
        O[(size_t)row * 1024 + col] = f2bf(acc[m][n][r]);
      }
}

// ---------------- flash attention; Q/K/V row strides qs/ks; AO stride 1024 -------------
__global__ __launch_bounds__(256) void attn_k(const u16* __restrict__ QH, const u16* __restrict__ KH,
                                              const u16* __restrict__ VH, u16* __restrict__ AO,
                                              const int* __restrict__ pmask, const float* __restrict__ Mrow,
                                              int Nq, int Nk, int qdiv, int pdiv, int qs, int ks) {
  __shared__ u16 Ks[32][72];
  __shared__ u16 Vt[64][40];
  __shared__ u16 Pl[4][16][40];
  const int tid = threadIdx.x;
  const int l = tid & 63, wid = tid >> 6;
  const int fr = l & 15, fg = l >> 4;
  const int nqb = Nq >> 6;
  const int wgid = swz8(blockIdx.x, gridDim.x);
  const int qb = wgid % nqb;
  const int bh = wgid / nqb;
  const int h = bh & 15, b = bh >> 4;
  const int q0 = qb * 64 + wid * 16;

  const size_t qrow = (size_t)(b * Nq + q0 + fr) * qs + h * 64;
  const bf16x8 aq0 = *(const bf16x8*)&QH[qrow + fg * 8];
  const bf16x8 aq1 = *(const bf16x8*)&QH[qrow + 32 + fg * 8];

  float Mr[4];
#pragma unroll
  for (int r = 0; r < 4; ++r) Mr[r] = Mrow[b * Tt + ((q0 + fg * 4 + r) >> 1)];

  f32x4 o[4];
#pragma unroll
  for (int c = 0; c < 4; ++c) o[c] = (f32x4){0.f, 0.f, 0.f, 0.f};
  float lsum[4] = {0.f, 0.f, 0.f, 0.f};

  int nkt = Nk >> 5;
  if (Mrow[b * Tt + ((qb * 64) >> 1)] == 0.0f) {
    const int kallow = (qb * 64 + 63) / qdiv + 1;
    const int t = (kallow + 31) >> 5;
    if (t < nkt) nkt = t;
  }

  const int srow = tid >> 3, skof = (tid & 7) << 3;
  for (int kt = 0; kt < nkt; ++kt) {
    const int kb = kt << 5;
    {
      const size_t g = (size_t)(b * Nk + kb + srow) * ks + h * 64 + skof;
      *(uint4*)&Ks[srow][skof] = *(const uint4*)&KH[g];
      union { uint4 u; u16 s[8]; } uv;
      uv.u = *(const uint4*)&VH[g];
#pragma unroll
      for (int j = 0; j < 8; ++j) Vt[skof + j][srow] = uv.s[j];
    }
    __syncthreads();

    f32x4 s0 = (f32x4){0.f, 0.f, 0.f, 0.f}, s1 = (f32x4){0.f, 0.f, 0.f, 0.f};
    {
      bf16x8 kf;
      kf = *(const bf16x8*)&Ks[fr][fg * 8];        s0 = mfma16(aq0, kf, s0);
      kf = *(const bf16x8*)&Ks[fr][32 + fg * 8];   s0 = mfma16(aq1, kf, s0);
      kf = *(const bf16x8*)&Ks[16 + fr][fg * 8];       s1 = mfma16(aq0, kf, s1);
      kf = *(const bf16x8*)&Ks[16 + fr][32 + fg * 8];  s1 = mfma16(aq1, kf, s1);
    }
    const int c0 = kb + fr, c1 = kb + 16 + fr;
    const float pad0 = pmask[b * Tt + c0 / pdiv] ? NEGV : 0.0f;
    const float pad1 = pmask[b * Tt + c1 / pdiv] ? NEGV : 0.0f;

#pragma unroll
    for (int r = 0; r < 4; ++r) {
      const int rq = (q0 + fg * 4 + r) / qdiv;
      float v0 = s0[r] * 0.125f; v0 = (c0 <= rq) ? v0 : NEGV; v0 += pad0;
      float v1 = s1[r] * 0.125f; v1 = (c1 <= rq) ? v1 : NEGV; v1 += pad1;
      const float p0 = __expf(v0 - Mr[r]);
      const float p1 = __expf(v1 - Mr[r]);
      lsum[r] += p0 + p1;
      Pl[wid][fg * 4 + r][fr] = f2bf(p0);
      Pl[wid][fg * 4 + r][16 + fr] = f2bf(p1);
    }

    const bf16x8 pa = *(const bf16x8*)&Pl[wid][fr][fg * 8];
#pragma unroll
    for (int c = 0; c < 4; ++c) {
      const bf16x8 vb = *(const bf16x8*)&Vt[c * 16 + fr][fg * 8];
      o[c] = mfma16(pa, vb, o[c]);
    }
    __syncthreads();
  }

#pragma unroll
  for (int r = 0; r < 4; ++r) {
    lsum[r] += __shfl_xor(lsum[r], 1);
    lsum[r] += __shfl_xor(lsum[r], 2);
    lsum[r] += __shfl_xor(lsum[r], 4);
    lsum[r] += __shfl_xor(lsum[r], 8);
  }

#pragma unroll
  for (int c = 0; c < 4; ++c)
#pragma unroll
    for (int r = 0; r < 4; ++r) {
      const int row = q0 + fg * 4 + r;
      AO[(size_t)(b * Nq + row) * Dd + h * 64 + c * 16 + fr] = f2bf(o[c][r] / lsum[r]);
    }
}

// =======================================================================================
extern "C" void kernel_launch(void* const* d_in, const int* in_sizes, int n_in,
                              void* d_out, int out_size, void* d_ws, size_t ws_size,
                              hipStream_t stream) {
  (void)in_sizes; (void)n_in; (void)out_size; (void)ws_size;
  const float* q_in   = (const float*)d_in[0];
  const float* c_in   = (const float*)d_in[1];
  const float* pe     = (const float*)d_in[2];
  const int*   pmask  = (const int*)d_in[3];
  const float* w_mod  = (const float*)d_in[4];
  const float* b_mod  = (const float*)d_in[5];
  const float* sa_wq  = (const float*)d_in[6];
  const float* sa_wk  = (const float*)d_in[7];
  const float* sa_wv  = (const float*)d_in[8];
  const float* sa_wo  = (const float*)d_in[9];
  const float* sa_bo  = (const float*)d_in[10];
  const float* ca_wq  = (const float*)d_in[11];
  const float* ca_wk  = (const float*)d_in[12];
  const float* ca_wv  = (const float*)d_in[13];
  const float* ca_wo  = (const float*)d_in[14];
  const float* ca_bo  = (const float*)d_in[15];
  const float* gk     = (const float*)d_in[16];
  const float* bk     = (const float*)d_in[17];
  const float* gv     = (const float*)d_in[18];
  const float* bv     = (const float*)d_in[19];
  const float* w_alpha= (const float*)d_in[20];
  const float* b_alpha= (const float*)d_in[21];
  const float* w1     = (const float*)d_in[22];
  const float* b1     = (const float*)d_in[23];
  const float* w2     = (const float*)d_in[24];
  const float* b2     = (const float*)d_in[25];

  // ---- workspace layout (u16 element offsets); same 155 MB footprint as before ----
  u16* ws = (u16*)d_ws;
  u16* WMODt  = ws + 0;                     // [6144][1024]; dead after mod GEMM
  float* Mp   = (float*)WMODt;              // [4][512] overlay (written after mod GEMM)
  u16* SAWQt  = ws + 6291456;               // SA Wq/Wk/Wv contiguous -> fused [3072][1024]
  u16* SAWKt  = ws + 7340032;
  u16* SAWVt  = ws + 8388608;
  u16* SAWOt  = ws + 9437184;
  u16* CAWQt  = ws + 10485760;
  u16* CAWKt  = ws + 11534336;
  u16* CAWVt  = ws + 12582912;
  u16* CAWOt  = ws + 13631488;
  u16* WALPHt = ws + 14680064;              // [1024][2048]
  u16* W1t    = ws + 16777216;              // [4096][1024]
  u16* W2t    = ws + 20971520;              // [1024][4096]
  u16* Xs     = ws + 25165824;              // [2048][1024] silu(c); dead after mod GEMM
  u16* KINp   = Xs;                         // [2048][1024] overlay on dead Xs
  u16* VINp   = SAWQt;                      // [2048][1024] overlay on dead SA Wq+Wk (post-QKV)
  u16* MODbf  = ws + 27262976;              // [2048][6144]
  u16* LNO    = ws + 39845888;              // [4096][1024]
  u16* BIG    = ws + 44040192;              // 16.77M u16, multi-use
  u16* QKVp = BIG;                          // [4096][3072] SA fused q/k/v
  u16* AOp  = BIG + 12582912;               // [4096][1024] SA attn out
  u16* CAQp = BIG;                          // CA buffers (SA dead)
  u16* CAKp = BIG + 4194304;
  u16* CAVp = BIG + 6291456;
  u16* AO2p = BIG + 8388608;                // [4096][1024] CA attn out
  u16* CATp = BIG;                          // [4096][2048] (CA q/k/v dead)
  float* ALPf = (float*)(BIG + 8388608);    // [4096][1024] f32 (AO2 dead)
  u16* HBp  = BIG;                          // [4096][4096] MLP hidden
  float* Qres = (float*)(ws + 60817408);    // [4096][1024] f32
  float* Q2f  = Qres + 4194304;             // [4096][1024] f32
  float* outp = (float*)d_out;

  const dim3 blk(256);
  auto TR = [&](const float* s, u16* d, int R, int C) {
    transpose_cast<<<dim3(C / 32, R / 32), dim3(32, 8), 0, stream>>>(s, d, R, C);
  };

  // weights -> bf16 transposed
  TR(w_mod, WMODt, 1024, 6144);
  TR(sa_wq, SAWQt, 1024, 1024); TR(sa_wk, SAWKt, 1024, 1024);
  TR(sa_wv, SAWVt, 1024, 1024); TR(sa_wo, SAWOt, 1024, 1024);
  TR(ca_wq, CAWQt, 1024, 1024); TR(ca_wk, CAWKt, 1024, 1024);
  TR(ca_wv, CAWVt, 1024, 1024); TR(ca_wo, CAWOt, 1024, 1024);
  TR(w_alpha, WALPHt, 2048, 1024);
  TR(w1, W1t, 1024, 4096);
  TR(w2, W2t, 4096, 1024);

  // modulation
  silu_k<<<8192, blk, 0, stream>>>(c_in, Xs, 2048 * 1024);
  gemm_k<1><<<768, blk, 0, stream>>>(Xs, WMODt, 6144, 1024, b_mod, MODbf, 48);
  mrow_k<<<1, 64, 0, stream>>>(pmask, Mp);           // Mp overlays dead WMODt

  // ---- self-attention ----
  ln_mod_k<<<4096, blk, 0, stream>>>(q_in, MODbf, LNO, 0);
  gemm_k<0><<<768, blk, 0, stream>>>(LNO, SAWQt, 3072, 1024, nullptr, QKVp, 24);   // fused QKV
  ln_kv_k<<<2048, blk, 0, stream>>>(c_in, pe, gk, bk, gv, bv, KINp, VINp);         // after QKV (VINp overlays)
  attn_k<<<1024, blk, 0, stream>>>(QKVp, QKVp + 1024, QKVp + 2048, AOp, pmask, Mp,
                                   1024, 1024, 1, 2, 3072, 3072);
  init_k<<<4096, blk, 0, stream>>>(Qres, sa_bo, q_in);
  gemm_sk<<<dim3(256, 2), blk, 0, stream>>>(AOp, SAWOt, 1024, 1024, Qres, 8);

  // ---- cross-attention ----
  ln_mod_k<<<4096, blk, 0, stream>>>(Qres, MODbf, LNO, 2);
  gemm3_k<<<dim3(256, 3), blk, 0, stream>>>(LNO, KINp, VINp, CAWQt, CAWKt, CAWVt, CAQp, CAKp, CAVp);
  attn_k<<<1024, blk, 0, stream>>>(CAQp, CAKp, CAVp, AO2p, pmask, Mp,
                                   1024, 512, 2, 1, 1024, 1024);
  init_k<<<4096, blk, 0, stream>>>(Q2f, ca_bo, nullptr);
  gemm_sk<<<dim3(256, 2), blk, 0, stream>>>(AO2p, CAWOt, 1024, 1024, Q2f, 8);
  cat_k<<<16384, blk, 0, stream>>>(Q2f, Qres, CATp);
  init_k<<<4096, blk, 0, stream>>>(ALPf, b_alpha, nullptr);
  gemm_sk<<<dim3(256, 2), blk, 0, stream>>>(CATp, WALPHt, 1024, 2048, ALPf, 8);
  comb_k<<<4096, blk, 0, stream>>>(ALPf, Q2f, Qres);

  // ---- MLP ----
  ln_mod_k<<<4096, blk, 0, stream>>>(Qres, MODbf, LNO, 4);
  gemm_k<2><<<1024, blk, 0, stream>>>(LNO, W1t, 4096, 1024, b1, HBp, 32);
  init_k<<<4096, blk, 0, stream>>>(outp, b2, Qres);
  gemm_sk<<<dim3(256, 2), blk, 0, stream>>>(HBp, W2t, 1024, 4096, outp, 8);
}

// Round 6
// 576.431 us; speedup vs baseline: 1.1924x; 1.1150x over previous
//
#include <hip/hip_runtime.h>
#include <cstdint>

typedef unsigned short u16;
typedef __attribute__((ext_vector_type(8))) short bf16x8;
typedef __attribute__((ext_vector_type(4))) float f32x4;

#define DEV static __device__ __forceinline__
#define AS1 __attribute__((address_space(1)))
#define AS3 __attribute__((address_space(3)))

static constexpr int Bb = 4, Tt = 512, Nn = 1024, Dd = 1024, Hh = 16;
static constexpr float NEGV = -10000.0f;

DEV u16 f2bf(float f) {
  unsigned int u = __builtin_bit_cast(unsigned int, f);
  u += 0x7fffu + ((u >> 16) & 1u);
  return (u16)(u >> 16);
}
DEV float bf2f(u16 s) {
  unsigned int u = ((unsigned int)s) << 16;
  return __builtin_bit_cast(float, u);
}
DEV f32x4 mfma16(bf16x8 a, bf16x8 b, f32x4 c) {
  return __builtin_amdgcn_mfma_f32_16x16x32_bf16(a, b, c, 0, 0, 0);
}
DEV void gload16(const u16* g, u16* lds) {
  __builtin_amdgcn_global_load_lds((AS1 const unsigned int*)g, (AS3 unsigned int*)lds, 16, 0, 0);
}
// chunked XCD swizzle; requires nwg % 8 == 0
DEV int swz8(int wg, int nwg) { const int c = nwg >> 3; return (wg & 7) * c + (wg >> 3); }

// ---------------- transpose + cast: src[R][C] f32 -> dst[C][R] bf16 -------------
__global__ __launch_bounds__(256) void transpose_cast(const float* __restrict__ src,
                                                      u16* __restrict__ dst, int R, int C) {
  __shared__ float tile[32][33];
  const int c0 = blockIdx.x * 32, r0 = blockIdx.y * 32;
  const int tx = threadIdx.x, ty = threadIdx.y;
#pragma unroll
  for (int j = 0; j < 4; ++j)
    tile[ty + 8 * j][tx] = src[(size_t)(r0 + ty + 8 * j) * C + c0 + tx];
  __syncthreads();
#pragma unroll
  for (int j = 0; j < 4; ++j)
    dst[(size_t)(c0 + ty + 8 * j) * R + r0 + tx] = f2bf(tile[tx][ty + 8 * j]);
}

// ---------------- silu(c) -> bf16 -------------
__global__ __launch_bounds__(256) void silu_k(const float* __restrict__ c, u16* __restrict__ o, int n) {
  int i = blockIdx.x * 256 + threadIdx.x;
  if (i < n) { float x = c[i]; o[i] = f2bf(x / (1.0f + __expf(-x))); }
}

// ---------------- build concat [q2 | q] bf16 -------------
__global__ __launch_bounds__(256) void cat_k(const float* __restrict__ q2, const float* __restrict__ qr,
                                             u16* __restrict__ cat) {
  int i = blockIdx.x * 256 + threadIdx.x;  // over 4096*1024
  int r = i >> 10, c = i & 1023;
  cat[(size_t)r * 2048 + c] = f2bf(q2[i]);
  cat[(size_t)r * 2048 + 1024 + c] = f2bf(qr[i]);
}

// ---------------- out[row][col] = bias[col] (+ res[row][col]) -------------
__global__ __launch_bounds__(256) void init_k(float* __restrict__ out, const float* __restrict__ bias,
                                              const float* __restrict__ res) {
  const int i = blockIdx.x * 256 + threadIdx.x;          // float4 index over 4096x1024
  const float4 bv = ((const float4*)bias)[i & 255];
  float4 v = bv;
  if (res) {
    const float4 rv = ((const float4*)res)[i];
    v.x += rv.x; v.y += rv.y; v.z += rv.z; v.w += rv.w;
  }
  ((float4*)out)[i] = v;
}

// ---------------- qres = (1+alp)*q2 + qres -------------
__global__ __launch_bounds__(256) void comb_k(const float* __restrict__ alp, const float* __restrict__ q2,
                                              float* __restrict__ qres) {
  const int i = blockIdx.x * 256 + threadIdx.x;          // float4 index
  const float4 a = ((const float4*)alp)[i];
  const float4 b = ((const float4*)q2)[i];
  float4 r = ((float4*)qres)[i];
  r.x += (1.0f + a.x) * b.x; r.y += (1.0f + a.y) * b.y;
  r.z += (1.0f + a.z) * b.z; r.w += (1.0f + a.w) * b.w;
  ((float4*)qres)[i] = r;
}

// ---------------- per-(b,t) softmax scale M: -1e4 if whole prefix padded, else 0 ----
__global__ __launch_bounds__(64) void mrow_k(const int* __restrict__ pm, float* __restrict__ M) {
  const int tid = threadIdx.x;            // 4 batches x 16 segments of 32
  const int b = tid >> 4, seg = tid & 15;
  int pre[32];
  int a = 1;
#pragma unroll
  for (int j = 0; j < 32; ++j) { a &= pm[b * 512 + seg * 32 + j]; pre[j] = a; }
  const int total = a;
  int excl = 1;
  for (int s = 0; s < 16; ++s) {
    int o = __shfl(total, (b << 4) + s, 64);
    if (s < seg) excl &= o;
  }
#pragma unroll
  for (int j = 0; j < 32; ++j)
    M[b * 512 + seg * 32 + j] = (excl & pre[j]) ? NEGV : 0.0f;
}

// ---------------- adaLN-modulated layernorm -------------
__global__ __launch_bounds__(256) void ln_mod_k(const float* __restrict__ X, const u16* __restrict__ MOD,
                                                u16* __restrict__ OUT, int chunk) {
  const int row = blockIdx.x;             // 0..4095
  const int b = row >> 10, i = row & 1023, t = i >> 1;
  const int tid = threadIdx.x;
  const float4 xv = *(const float4*)&X[(size_t)row * 1024 + tid * 4];
  float s = xv.x + xv.y + xv.z + xv.w;
  float q = xv.x * xv.x + xv.y * xv.y + xv.z * xv.z + xv.w * xv.w;
#pragma unroll
  for (int off = 32; off > 0; off >>= 1) { s += __shfl_down(s, off); q += __shfl_down(q, off); }
  __shared__ float rs[4], rq[4];
  if ((tid & 63) == 0) { rs[tid >> 6] = s; rq[tid >> 6] = q; }
  __syncthreads();
  float S = rs[0] + rs[1] + rs[2] + rs[3];
  float Q = rq[0] + rq[1] + rq[2] + rq[3];
  const float mu = S * (1.0f / 1024.0f);
  const float var = Q * (1.0f / 1024.0f) - mu * mu;
  const float rstd = rsqrtf(var + 1e-6f);
  const u16* mrow = MOD + (size_t)(b * Tt + t) * 6144 + chunk * 1024 + tid * 4;
  u16* out = OUT + (size_t)row * 1024 + tid * 4;
  const float xx[4] = {xv.x, xv.y, xv.z, xv.w};
#pragma unroll
  for (int j = 0; j < 4; ++j) {
    float sc = bf2f(mrow[j]);
    float sh = bf2f(mrow[1024 + j]);
    out[j] = f2bf((xx[j] - mu) * rstd * (1.0f + sc) + sh);
  }
}

// ---------------- kin = ln(c+pe)*gk+bk ; vin = ln(c)*gv+bv -------------
__global__ __launch_bounds__(256) void ln_kv_k(const float* __restrict__ C_, const float* __restrict__ PE,
                                               const float* __restrict__ gk, const float* __restrict__ bk,
                                               const float* __restrict__ gv, const float* __restrict__ bv,
                                               u16* __restrict__ KIN, u16* __restrict__ VIN) {
  const int row = blockIdx.x, tid = threadIdx.x;  // rows 0..2047
  const size_t base = (size_t)row * 1024 + tid * 4;
  const float4 cv = *(const float4*)&C_[base];
  const float4 pv = *(const float4*)&PE[base];
  const float a[4] = {cv.x + pv.x, cv.y + pv.y, cv.z + pv.z, cv.w + pv.w};
  const float bb[4] = {cv.x, cv.y, cv.z, cv.w};
  float sa = a[0] + a[1] + a[2] + a[3];
  float qa = a[0] * a[0] + a[1] * a[1] + a[2] * a[2] + a[3] * a[3];
  float sb = bb[0] + bb[1] + bb[2] + bb[3];
  float qb = bb[0] * bb[0] + bb[1] * bb[1] + bb[2] * bb[2] + bb[3] * bb[3];
#pragma unroll
  for (int off = 32; off > 0; off >>= 1) {
    sa += __shfl_down(sa, off); qa += __shfl_down(qa, off);
    sb += __shfl_down(sb, off); qb += __shfl_down(qb, off);
  }
  __shared__ float r4[4][4];
  if ((tid & 63) == 0) {
    int w = tid >> 6;
    r4[0][w] = sa; r4[1][w] = qa; r4[2][w] = sb; r4[3][w] = qb;
  }
  __syncthreads();
  sa = r4[0][0] + r4[0][1] + r4[0][2] + r4[0][3];
  qa = r4[1][0] + r4[1][1] + r4[1][2] + r4[1][3];
  sb = r4[2][0] + r4[2][1] + r4[2][2] + r4[2][3];
  qb = r4[3][0] + r4[3][1] + r4[3][2] + r4[3][3];
  const float mua = sa * (1.0f / 1024.0f);
  const float ra = rsqrtf(qa * (1.0f / 1024.0f) - mua * mua + 1e-5f);
  const float mub = sb * (1.0f / 1024.0f);
  const float rb = rsqrtf(qb * (1.0f / 1024.0f) - mub * mub + 1e-5f);
#pragma unroll
  for (int j = 0; j < 4; ++j) {
    int d = tid * 4 + j;
    KIN[(size_t)row * 1024 + d] = f2bf((a[j] - mua) * ra * gk[d] + bk[d]);
    VIN[(size_t)row * 1024 + d] = f2bf((bb[j] - mub) * rb * gv[d] + bv[d]);
  }
}

// ---------------- double-buffered GEMM core (T3 minimum-2-phase, BK=32) ----------------
// stage one 128x32 A-tile + B-tile (8KB each) via global_load_lds
DEV void stage32(const u16* __restrict__ A, const u16* __restrict__ Bt, int K,
                 int brow, int bcol, int kb, u16 (*As)[32], u16 (*Bs)[32]) {
  const int l = threadIdx.x & 63, wid = threadIdx.x >> 6;
#pragma unroll
  for (int p = 0; p < 2; ++p) {
    const int r0 = p * 64 + wid * 16;
    const int row = r0 + (l >> 2), kof = (l & 3) << 3;
    gload16(&A[(size_t)(brow + row) * K + kb + kof], &As[r0][0]);
    gload16(&Bt[(size_t)(bcol + row) * K + kb + kof], &Bs[r0][0]);
  }
}

// acc += A[brow..+128][k0..k0+nk32*32) x Bt[bcol..+128][...]^T
DEV void gcore(const u16* __restrict__ A, const u16* __restrict__ Bt, int K,
               int brow, int bcol, int k0, int nk32,
               u16 (*As)[128][32], u16 (*Bs)[128][32], f32x4 (&acc)[4][4]) {
  const int l = threadIdx.x & 63, wid = threadIdx.x >> 6;
  const int wr = wid >> 1, wc = wid & 1;
  const int fr = l & 15, fg = l >> 4;
  stage32(A, Bt, K, brow, bcol, k0, As[0], Bs[0]);
  __syncthreads();                       // drains vmcnt(0)
  int cur = 0;
  for (int kt = 0; kt < nk32; ++kt) {
    if (kt + 1 < nk32)                   // issue next tile BEFORE compute
      stage32(A, Bt, K, brow, bcol, k0 + ((kt + 1) << 5), As[cur ^ 1], Bs[cur ^ 1]);
    bf16x8 af[4], bfr[4];
#pragma unroll
    for (int m = 0; m < 4; ++m) af[m] = *(const bf16x8*)&As[cur][wr * 64 + m * 16 + fr][fg * 8];
#pragma unroll
    for (int n = 0; n < 4; ++n) bfr[n] = *(const bf16x8*)&Bs[cur][wc * 64 + n * 16 + fr][fg * 8];
#pragma unroll
    for (int m = 0; m < 4; ++m)
#pragma unroll
      for (int n = 0; n < 4; ++n) acc[m][n] = mfma16(af[m], bfr[n], acc[m][n]);
    __syncthreads();                     // one barrier/K-step; drains vmcnt for next buf
    cur ^= 1;
  }
}

// ---------------- generic GEMM, 1D swizzled grid -------------
// EPI 0: bf16 out   1: bf16+bias   2: bf16+bias+gelu(sigmoid form)
template <int EPI>
__global__ __launch_bounds__(256) void gemm_k(const u16* __restrict__ A, const u16* __restrict__ Bt,
                                              int N, int K, const float* __restrict__ bias,
                                              u16* __restrict__ outb, int nbx) {
  __shared__ u16 As[2][128][32];
  __shared__ u16 Bs[2][128][32];
  const int wg = swz8(blockIdx.x, gridDim.x);
  const int brow = (wg / nbx) * 128, bcol = (wg % nbx) * 128;
  const int l = threadIdx.x & 63, wid = threadIdx.x >> 6;
  const int wr = wid >> 1, wc = wid & 1, fr = l & 15, fg = l >> 4;
  f32x4 acc[4][4];
#pragma unroll
  for (int m = 0; m < 4; ++m)
#pragma unroll
    for (int n = 0; n < 4; ++n) acc[m][n] = (f32x4){0.f, 0.f, 0.f, 0.f};
  gcore(A, Bt, K, brow, bcol, 0, K >> 5, As, Bs, acc);
#pragma unroll
  for (int m = 0; m < 4; ++m)
#pragma unroll
    for (int n = 0; n < 4; ++n)
#pragma unroll
      for (int r = 0; r < 4; ++r) {
        const int row = brow + wr * 64 + m * 16 + fg * 4 + r;
        const int col = bcol + wc * 64 + n * 16 + fr;
        float v = acc[m][n][r];
        if (EPI != 0) v += bias[col];
        if (EPI == 2) {  // gelu, sigmoid form of tanh-approx (|dev from erf| < 3e-3)
          const float u = v * (0.7978845608f + 0.0356774081f * v * v);
          v = v / (1.0f + __expf(-2.0f * u));
        }
        outb[(size_t)row * N + col] = f2bf(v);
      }
}

// ---------------- split-K=2 GEMM, f32 atomicAdd epilogue -------------
__global__ __launch_bounds__(256) void gemm_sk(const u16* __restrict__ A, const u16* __restrict__ Bt,
                                               int N, int K, float* __restrict__ outf, int nbx) {
  __shared__ u16 As[2][128][32];
  __shared__ u16 Bs[2][128][32];
  const int wg = swz8(blockIdx.x, gridDim.x);
  const int brow = (wg / nbx) * 128, bcol = (wg % nbx) * 128;
  const int half32 = K >> 6;                     // 32-wide k-tiles per half
  const int k0 = blockIdx.y * (half32 << 5);
  const int l = threadIdx.x & 63, wid = threadIdx.x >> 6;
  const int wr = wid >> 1, wc = wid & 1, fr = l & 15, fg = l >> 4;
  f32x4 acc[4][4];
#pragma unroll
  for (int m = 0; m < 4; ++m)
#pragma unroll
    for (int n = 0; n < 4; ++n) acc[m][n] = (f32x4){0.f, 0.f, 0.f, 0.f};
  gcore(A, Bt, K, brow, bcol, k0, half32, As, Bs, acc);
#pragma unroll
  for (int m = 0; m < 4; ++m)
#pragma unroll
    for (int n = 0; n < 4; ++n)
#pragma unroll
      for (int r = 0; r < 4; ++r) {
        const int row = brow + wr * 64 + m * 16 + fg * 4 + r;
        const int col = bcol + wc * 64 + n * 16 + fr;
        atomicAdd(&outf[(size_t)row * N + col], acc[m][n][r]);
      }
}

// ---------------- CA grouped GEMM: z=0 Q(M=4096), z=1 K(M=2048), z=2 V(M=2048); N=K=1024 ----
__global__ __launch_bounds__(256) void gemm3_k(const u16* A0, const u16* A1, const u16* A2,
                                               const u16* B0, const u16* B1, const u16* B2,
                                               u16* O0, u16* O1, u16* O2) {
  const int z = blockIdx.y;
  const int wg = swz8(blockIdx.x, gridDim.x);
  const int bx = wg & 7, by = wg >> 3;
  if (z > 0 && by >= 16) return;
  const u16* A = z == 0 ? A0 : (z == 1 ? A1 : A2);
  const u16* Bt = z == 0 ? B0 : (z == 1 ? B1 : B2);
  u16* O = z == 0 ? O0 : (z == 1 ? O1 : O2);
  __shared__ u16 As[2][128][32];
  __shared__ u16 Bs[2][128][32];
  const int brow = by * 128, bcol = bx * 128;
  const int l = threadIdx.x & 63, wid = threadIdx.x >> 6;
  const int wr = wid >> 1, wc = wid & 1, fr = l & 15, fg = l >> 4;
  f32x4 acc[4][4];
#pragma unroll
  for (int m = 0; m < 4; ++m)
#pragma unroll
    for (int n = 0; n < 4; ++n) acc[m][n] = (f32x4){0.f, 0.f, 0.f, 0.f};
  gcore(A, Bt, 1024, brow, bcol, 0, 32, As, Bs, acc);
#pragma unroll
  for (int m = 0; m < 4; ++m)
#pragma unroll
    for (int n = 0; n < 4; ++n)
#pragma unroll
      for (int r = 0; r < 4; ++r) {
        const int row = brow + wr * 64 + m * 16 + fg * 4 + r;
        const int col = bcol + wc * 64 + n * 16 + fr;
        O[(size_t)row * 1024 + col] = f2bf(acc[m][n][r]);
      }
}

// ---------------- flash attention; compile-time qdiv/pdiv -------------
template <int QDIV, int PDIV>
__global__ __launch_bounds__(256) void attn_k(const u16* __restrict__ QH, const u16* __restrict__ KH,
                                              const u16* __restrict__ VH, u16* __restrict__ AO,
                                              const int* __restrict__ pmask, const float* __restrict__ Mrow,
                                              int Nq, int Nk, int qs, int ks) {
  __shared__ u16 Ks[32][72];
  __shared__ u16 Vt[64][40];
  __shared__ u16 Pl[4][16][40];
  const int tid = threadIdx.x;
  const int l = tid & 63, wid = tid >> 6;
  const int fr = l & 15, fg = l >> 4;
  const int nqb = Nq >> 6;
  const int wgid = swz8(blockIdx.x, gridDim.x);
  const int qb = wgid % nqb;
  const int bh = wgid / nqb;
  const int h = bh & 15, b = bh >> 4;
  const int q0 = qb * 64 + wid * 16;

  const size_t qrow = (size_t)(b * Nq + q0 + fr) * qs + h * 64;
  const bf16x8 aq0 = *(const bf16x8*)&QH[qrow + fg * 8];
  const bf16x8 aq1 = *(const bf16x8*)&QH[qrow + 32 + fg * 8];

  float Mr[4];
#pragma unroll
  for (int r = 0; r < 4; ++r) Mr[r] = Mrow[b * Tt + ((q0 + fg * 4 + r) >> 1)];

  f32x4 o[4];
#pragma unroll
  for (int c = 0; c < 4; ++c) o[c] = (f32x4){0.f, 0.f, 0.f, 0.f};
  float lsum[4] = {0.f, 0.f, 0.f, 0.f};

  int nkt = Nk >> 5;
  if (Mrow[b * Tt + ((qb * 64) >> 1)] == 0.0f) {
    const int kallow = (qb * 64 + 63) / QDIV + 1;
    const int t = (kallow + 31) >> 5;
    if (t < nkt) nkt = t;
  }

  const int srow = tid >> 3, skof = (tid & 7) << 3;
  for (int kt = 0; kt < nkt; ++kt) {
    const int kb = kt << 5;
    {
      const size_t g = (size_t)(b * Nk + kb + srow) * ks + h * 64 + skof;
      *(uint4*)&Ks[srow][skof] = *(const uint4*)&KH[g];
      union { uint4 u; u16 s[8]; } uv;
      uv.u = *(const uint4*)&VH[g];
#pragma unroll
      for (int j = 0; j < 8; ++j) Vt[skof + j][srow] = uv.s[j];
    }
    __syncthreads();

    f32x4 s0 = (f32x4){0.f, 0.f, 0.f, 0.f}, s1 = (f32x4){0.f, 0.f, 0.f, 0.f};
    {
      bf16x8 kf;
      kf = *(const bf16x8*)&Ks[fr][fg * 8];        s0 = mfma16(aq0, kf, s0);
      kf = *(const bf16x8*)&Ks[fr][32 + fg * 8];   s0 = mfma16(aq1, kf, s0);
      kf = *(const bf16x8*)&Ks[16 + fr][fg * 8];       s1 = mfma16(aq0, kf, s1);
      kf = *(const bf16x8*)&Ks[16 + fr][32 + fg * 8];  s1 = mfma16(aq1, kf, s1);
    }
    const int c0 = kb + fr, c1 = kb + 16 + fr;
    const float pad0 = pmask[b * Tt + (PDIV == 2 ? (c0 >> 1) : c0)] ? NEGV : 0.0f;
    const float pad1 = pmask[b * Tt + (PDIV == 2 ? (c1 >> 1) : c1)] ? NEGV : 0.0f;

#pragma unroll
    for (int r = 0; r < 4; ++r) {
      const int rq = (q0 + fg * 4 + r) >> (QDIV == 2 ? 1 : 0);
      float v0 = s0[r] * 0.125f; v0 = (c0 <= rq) ? v0 : NEGV; v0 += pad0;
      float v1 = s1[r] * 0.125f; v1 = (c1 <= rq) ? v1 : NEGV; v1 += pad1;
      const float p0 = __expf(v0 - Mr[r]);
      const float p1 = __expf(v1 - Mr[r]);
      lsum[r] += p0 + p1;
      Pl[wid][fg * 4 + r][fr] = f2bf(p0);
      Pl[wid][fg * 4 + r][16 + fr] = f2bf(p1);
    }

    const bf16x8 pa = *(const bf16x8*)&Pl[wid][fr][fg * 8];
#pragma unroll
    for (int c = 0; c < 4; ++c) {
      const bf16x8 vb = *(const bf16x8*)&Vt[c * 16 + fr][fg * 8];
      o[c] = mfma16(pa, vb, o[c]);
    }
    __syncthreads();
  }

#pragma unroll
  for (int r = 0; r < 4; ++r) {
    lsum[r] += __shfl_xor(lsum[r], 1);
    lsum[r] += __shfl_xor(lsum[r], 2);
    lsum[r] += __shfl_xor(lsum[r], 4);
    lsum[r] += __shfl_xor(lsum[r], 8);
  }

#pragma unroll
  for (int c = 0; c < 4; ++c)
#pragma unroll
    for (int r = 0; r < 4; ++r) {
      const int row = q0 + fg * 4 + r;
      AO[(size_t)(b * Nq + row) * Dd + h * 64 + c * 16 + fr] = f2bf(o[c][r] / lsum[r]);
    }
}

// =======================================================================================
extern "C" void kernel_launch(void* const* d_in, const int* in_sizes, int n_in,
                              void* d_out, int out_size, void* d_ws, size_t ws_size,
                              hipStream_t stream) {
  (void)in_sizes; (void)n_in; (void)out_size; (void)ws_size;
  const float* q_in   = (const float*)d_in[0];
  const float* c_in   = (const float*)d_in[1];
  const float* pe     = (const float*)d_in[2];
  const int*   pmask  = (const int*)d_in[3];
  const float* w_mod  = (const float*)d_in[4];
  const float* b_mod  = (const float*)d_in[5];
  const float* sa_wq  = (const float*)d_in[6];
  const float* sa_wk  = (const float*)d_in[7];
  const float* sa_wv  = (const float*)d_in[8];
  const float* sa_wo  = (const float*)d_in[9];
  const float* sa_bo  = (const float*)d_in[10];
  const float* ca_wq  = (const float*)d_in[11];
  const float* ca_wk  = (const float*)d_in[12];
  const float* ca_wv  = (const float*)d_in[13];
  const float* ca_wo  = (const float*)d_in[14];
  const float* ca_bo  = (const float*)d_in[15];
  const float* gk     = (const float*)d_in[16];
  const float* bk     = (const float*)d_in[17];
  const float* gv     = (const float*)d_in[18];
  const float* bv     = (const float*)d_in[19];
  const float* w_alpha= (const float*)d_in[20];
  const float* b_alpha= (const float*)d_in[21];
  const float* w1     = (const float*)d_in[22];
  const float* b1     = (const float*)d_in[23];
  const float* w2     = (const float*)d_in[24];
  const float* b2     = (const float*)d_in[25];

  // ---- workspace layout (u16 element offsets) ----
  u16* ws = (u16*)d_ws;
  u16* WMODt  = ws + 0;                     // [6144][1024]; dead after mod GEMM
  float* Mp   = (float*)WMODt;              // [4][512] overlay (written after mod GEMM)
  u16* SAWQt  = ws + 6291456;               // SA Wq/Wk/Wv contiguous -> fused [3072][1024]
  u16* SAWKt  = ws + 7340032;
  u16* SAWVt  = ws + 8388608;
  u16* SAWOt  = ws + 9437184;
  u16* CAWQt  = ws + 10485760;
  u16* CAWKt  = ws + 11534336;
  u16* CAWVt  = ws + 12582912;
  u16* CAWOt  = ws + 13631488;
  u16* WALPHt = ws + 14680064;              // [1024][2048]
  u16* W1t    = ws + 16777216;              // [4096][1024]
  u16* W2t    = ws + 20971520;              // [1024][4096]
  u16* Xs     = ws + 25165824;              // [2048][1024] silu(c); dead after mod GEMM
  u16* KINp   = Xs;                         // [2048][1024] overlay on dead Xs
  u16* VINp   = SAWQt;                      // [2048][1024] overlay on dead SA Wq+Wk (post-QKV)
  u16* MODbf  = ws + 27262976;              // [2048][6144]
  u16* LNO    = ws + 39845888;              // [4096][1024]
  u16* BIG    = ws + 44040192;              // 16.77M u16, multi-use
  u16* QKVp = BIG;                          // [4096][3072] SA fused q/k/v
  u16* AOp  = BIG + 12582912;               // [4096][1024] SA attn out
  u16* CAQp = BIG;                          // CA buffers (SA dead)
  u16* CAKp = BIG + 4194304;
  u16* CAVp = BIG + 6291456;
  u16* AO2p = BIG + 8388608;                // [4096][1024] CA attn out
  u16* CATp = BIG;                          // [4096][2048] (CA q/k/v dead)
  float* ALPf = (float*)(BIG + 8388608);    // [4096][1024] f32 (AO2 dead)
  u16* HBp  = BIG;                          // [4096][4096] MLP hidden
  float* Qres = (float*)(ws + 60817408);    // [4096][1024] f32
  float* Q2f  = Qres + 4194304;             // [4096][1024] f32
  float* outp = (float*)d_out;

  const dim3 blk(256);
  auto TR = [&](const float* s, u16* d, int R, int C) {
    transpose_cast<<<dim3(C / 32, R / 32), dim3(32, 8), 0, stream>>>(s, d, R, C);
  };

  // weights -> bf16 transposed
  TR(w_mod, WMODt, 1024, 6144);
  TR(sa_wq, SAWQt, 1024, 1024); TR(sa_wk, SAWKt, 1024, 1024);
  TR(sa_wv, SAWVt, 1024, 1024); TR(sa_wo, SAWOt, 1024, 1024);
  TR(ca_wq, CAWQt, 1024, 1024); TR(ca_wk, CAWKt, 1024, 1024);
  TR(ca_wv, CAWVt, 1024, 1024); TR(ca_wo, CAWOt, 1024, 1024);
  TR(w_alpha, WALPHt, 2048, 1024);
  TR(w1, W1t, 1024, 4096);
  TR(w2, W2t, 4096, 1024);

  // modulation
  silu_k<<<8192, blk, 0, stream>>>(c_in, Xs, 2048 * 1024);
  gemm_k<1><<<768, blk, 0, stream>>>(Xs, WMODt, 6144, 1024, b_mod, MODbf, 48);
  mrow_k<<<1, 64, 0, stream>>>(pmask, Mp);           // Mp overlays dead WMODt

  // ---- self-attention ----
  ln_mod_k<<<4096, blk, 0, stream>>>(q_in, MODbf, LNO, 0);
  gemm_k<0><<<768, blk, 0, stream>>>(LNO, SAWQt, 3072, 1024, nullptr, QKVp, 24);   // fused QKV
  ln_kv_k<<<2048, blk, 0, stream>>>(c_in, pe, gk, bk, gv, bv, KINp, VINp);         // after QKV (VINp overlays)
  attn_k<1, 2><<<1024, blk, 0, stream>>>(QKVp, QKVp + 1024, QKVp + 2048, AOp, pmask, Mp,
                                         1024, 1024, 3072, 3072);
  init_k<<<4096, blk, 0, stream>>>(Qres, sa_bo, q_in);
  gemm_sk<<<dim3(256, 2), blk, 0, stream>>>(AOp, SAWOt, 1024, 1024, Qres, 8);

  // ---- cross-attention ----
  ln_mod_k<<<4096, blk, 0, stream>>>(Qres, MODbf, LNO, 2);
  gemm3_k<<<dim3(256, 3), blk, 0, stream>>>(LNO, KINp, VINp, CAWQt, CAWKt, CAWVt, CAQp, CAKp, CAVp);
  attn_k<2, 1><<<1024, blk, 0, stream>>>(CAQp, CAKp, CAVp, AO2p, pmask, Mp,
                                         1024, 512, 1024, 1024);
  init_k<<<4096, blk, 0, stream>>>(Q2f, ca_bo, nullptr);
  gemm_sk<<<dim3(256, 2), blk, 0, stream>>>(AO2p, CAWOt, 1024, 1024, Q2f, 8);
  cat_k<<<16384, blk, 0, stream>>>(Q2f, Qres, CATp);
  init_k<<<4096, blk, 0, stream>>>(ALPf, b_alpha, nullptr);
  gemm_sk<<<dim3(256, 2), blk, 0, stream>>>(CATp, WALPHt, 1024, 2048, ALPf, 8);
  comb_k<<<4096, blk, 0, stream>>>(ALPf, Q2f, Qres);

  // ---- MLP ----
  ln_mod_k<<<4096, blk, 0, stream>>>(Qres, MODbf, LNO, 4);
  gemm_k<2><<<1024, blk, 0, stream>>>(LNO, W1t, 4096, 1024, b1, HBp, 32);
  init_k<<<4096, blk, 0, stream>>>(outp, b2, Qres);
  gemm_sk<<<dim3(256, 2), blk, 0, stream>>>(HBp, W2t, 1024, 4096, outp, 8);
}